// Round 2
// baseline (4811.158 us; speedup 1.0000x reference)
//
#include <hip/hip_runtime.h>
#include <hip/hip_bf16.h>
#include <math.h>

#define HEADS 4
#define HID 610
#define FIN 128
#define KER 50
#define NOUT 86
#define NEG_SLOPE 0.2f

// ---------------- utility: fill ----------------
__global__ void fill_val(float* __restrict__ p, float v, long n) {
    long i = (long)blockIdx.x * blockDim.x + threadIdx.x;
    if (i < n) p[i] = v;
}

// ---------------- fp32 tiled GEMM: C[M,N] = A[M,K] * B[N,K]^T (+bias) ----------------
template <bool BIAS>
__global__ __launch_bounds__(256) void gemm_nt(const float* __restrict__ A,
                                               const float* __restrict__ B,
                                               const float* __restrict__ bias,
                                               float* __restrict__ C,
                                               int M, int N, int K) {
    const int BM = 64, BN = 64, BK = 16, TM = 4, TN = 4;
    __shared__ float As[BK][BM + 1];
    __shared__ float Bs[BK][BN + 1];
    int tid = threadIdx.x;
    int tr = tid / 16, tc = tid % 16;
    int row0 = blockIdx.y * BM;
    int col0 = blockIdx.x * BN;
    float acc[TM][TN] = {};
    for (int k0 = 0; k0 < K; k0 += BK) {
        for (int t = tid; t < BM * BK; t += 256) {
            int i = t / BK, j = t % BK;
            int r = row0 + i, c = k0 + j;
            As[j][i] = (r < M && c < K) ? A[(long)r * K + c] : 0.f;
        }
        for (int t = tid; t < BN * BK; t += 256) {
            int i = t / BK, j = t % BK;
            int r = col0 + i, c = k0 + j;
            Bs[j][i] = (r < N && c < K) ? B[(long)r * K + c] : 0.f;
        }
        __syncthreads();
#pragma unroll
        for (int kk = 0; kk < BK; ++kk) {
            float a[TM], b[TN];
#pragma unroll
            for (int i = 0; i < TM; i++) a[i] = As[kk][tr * TM + i];
#pragma unroll
            for (int j = 0; j < TN; j++) b[j] = Bs[kk][tc * TN + j];
#pragma unroll
            for (int i = 0; i < TM; i++)
#pragma unroll
                for (int j = 0; j < TN; j++) acc[i][j] += a[i] * b[j];
        }
        __syncthreads();
    }
#pragma unroll
    for (int i = 0; i < TM; i++) {
        int r = row0 + tr * TM + i;
        if (r >= M) continue;
#pragma unroll
        for (int j = 0; j < TN; j++) {
            int c = col0 + tc * TN + j;
            if (c >= N) continue;
            float v = acc[i][j];
            if (BIAS) v += bias[c];
            C[(long)r * N + c] = v;
        }
    }
}

// ---------------- attention dot products per node/head ----------------
__global__ __launch_bounds__(256) void attn_dots(const float* __restrict__ h,
                                                 const float* __restrict__ att_s,
                                                 const float* __restrict__ att_d,
                                                 float* __restrict__ a_src,
                                                 float* __restrict__ a_dst, int Nn) {
    int n = blockIdx.x;
    int head = threadIdx.x >> 6;
    int lane = threadIdx.x & 63;
    const float* hr = h + (long)n * (HEADS * HID) + head * HID;
    const float* as = att_s + head * HID;
    const float* ad = att_d + head * HID;
    float ss = 0.f, sd = 0.f;
    for (int d = lane; d < HID; d += 64) {
        float hv = hr[d];
        ss += hv * as[d];
        sd += hv * ad[d];
    }
    for (int off = 32; off > 0; off >>= 1) {
        ss += __shfl_down(ss, off);
        sd += __shfl_down(sd, off);
    }
    if (lane == 0) {
        a_src[n * HEADS + head] = ss;
        a_dst[n * HEADS + head] = sd;
    }
}

// ---------------- edge alpha + segment max ----------------
__device__ inline void atomicMaxFloat(float* addr, float val) {
    int* ia = (int*)addr;
    int old = __float_as_int(*addr);
    while (__int_as_float(old) < val) {
        int assumed = old;
        old = atomicCAS(ia, assumed, __float_as_int(val));
        if (old == assumed) break;
    }
}

__global__ void edge_alpha_max(const float* __restrict__ a_src, const float* __restrict__ a_dst,
                               const int* __restrict__ ei, float* __restrict__ alpha,
                               float* __restrict__ m, int E) {
    int e = blockIdx.x * blockDim.x + threadIdx.x;
    if (e >= E) return;
    int s = ei[e];
    int d = ei[E + e];
#pragma unroll
    for (int hh = 0; hh < HEADS; hh++) {
        float v = a_src[s * HEADS + hh] + a_dst[d * HEADS + hh];
        v = v >= 0.f ? v : NEG_SLOPE * v;
        alpha[(long)e * HEADS + hh] = v;
        atomicMaxFloat(&m[d * HEADS + hh], v);
    }
}

__global__ void edge_exp_sum(const int* __restrict__ ei, float* __restrict__ alpha,
                             const float* __restrict__ m, float* __restrict__ denom, int E) {
    int e = blockIdx.x * blockDim.x + threadIdx.x;
    if (e >= E) return;
    int d = ei[E + e];
#pragma unroll
    for (int hh = 0; hh < HEADS; hh++) {
        float v = expf(alpha[(long)e * HEADS + hh] - m[d * HEADS + hh]);
        alpha[(long)e * HEADS + hh] = v;
        atomicAdd(&denom[d * HEADS + hh], v);
    }
}

// ---------------- message aggregation: agg[dst,d] += sum_h 0.25*a[e,h]*h[src,h,d] ----------------
__global__ __launch_bounds__(256) void edge_message(const float* __restrict__ h,
                                                    const int* __restrict__ ei,
                                                    const float* __restrict__ eexp,
                                                    const float* __restrict__ denom,
                                                    float* __restrict__ agg, int E) {
    int e = blockIdx.x;
    int s = ei[e];
    int d = ei[E + e];
    float coef[HEADS];
#pragma unroll
    for (int hh = 0; hh < HEADS; hh++)
        coef[hh] = 0.25f * eexp[(long)e * HEADS + hh] / (denom[d * HEADS + hh] + 1e-16f);
    const float* hr = h + (long)s * (HEADS * HID);
    float* ar = agg + (long)d * HID;
    for (int dd = threadIdx.x; dd < HID; dd += blockDim.x) {
        float v = coef[0] * hr[dd] + coef[1] * hr[HID + dd] + coef[2] * hr[2 * HID + dd] +
                  coef[3] * hr[3 * HID + dd];
        atomicAdd(&ar[dd], v);
    }
}

// ---------------- node epilogue: x = relu(agg + b) (safe in-place) ----------------
__global__ void node_epi(const float* __restrict__ agg, const float* __restrict__ bias,
                         float* __restrict__ xout, long total) {
    long i = (long)blockIdx.x * blockDim.x + threadIdx.x;
    if (i >= total) return;
    int dcol = (int)(i % HID);
    float v = agg[i] + bias[dcol];
    xout[i] = v > 0.f ? v : 0.f;
}

// ---------------- fused edge conv: x2[src],x2[dst] -> y[561] -> z[512] ----------------
__global__ __launch_bounds__(256) void edge_conv(const float* __restrict__ x2,
                                                 const int* __restrict__ ei,
                                                 const float* __restrict__ w4,
                                                 const float* __restrict__ b4,
                                                 const float* __restrict__ w6,
                                                 const float* __restrict__ b6,
                                                 float* __restrict__ z, int E) {
    __shared__ float s[HID];
    __shared__ float t[HID];
    __shared__ float y[HID - KER + 1];  // 561
    __shared__ float w4s[2 * KER];
    __shared__ float w6s[KER];
    int e = blockIdx.x;
    int sidx = ei[e];
    int didx = ei[E + e];
    const float* sp = x2 + (long)sidx * HID;
    const float* tp = x2 + (long)didx * HID;
    for (int i = threadIdx.x; i < HID; i += blockDim.x) {
        s[i] = sp[i];
        t[i] = tp[i];
    }
    if (threadIdx.x < 2 * KER)
        w4s[threadIdx.x] = w4[threadIdx.x];
    else if (threadIdx.x < 3 * KER)
        w6s[threadIdx.x - 2 * KER] = w6[threadIdx.x - 2 * KER];
    __syncthreads();
    float bb4 = b4[0], bb6 = b6[0];
    for (int j = threadIdx.x; j < HID - KER + 1; j += blockDim.x) {
        float acc = bb4;
#pragma unroll
        for (int k = 0; k < KER; k++) acc += s[j + k] * w4s[k] + t[j + k] * w4s[KER + k];
        y[j] = acc > 0.f ? acc : 0.f;
    }
    __syncthreads();
    for (int j = threadIdx.x; j < 512; j += blockDim.x) {
        float acc = bb6;
#pragma unroll
        for (int k = 0; k < KER; k++) acc += y[j + k] * w6s[k];
        z[(long)e * 512 + j] = acc > 0.f ? acc : 0.f;
    }
}

extern "C" void kernel_launch(void* const* d_in, const int* in_sizes, int n_in,
                              void* d_out, int out_size, void* d_ws, size_t ws_size,
                              hipStream_t stream) {
    const float* x = (const float*)d_in[0];
    const int* ei = (const int*)d_in[1];  // int32! (JAX demotes int64 w/o x64)
    const float* w0 = (const float*)d_in[2];
    const float* b0 = (const float*)d_in[3];
    const float* att_s0 = (const float*)d_in[4];
    const float* att_d0 = (const float*)d_in[5];
    const float* w2 = (const float*)d_in[6];
    const float* b2 = (const float*)d_in[7];
    const float* att_s1 = (const float*)d_in[8];
    const float* att_d1 = (const float*)d_in[9];
    const float* w4 = (const float*)d_in[10];
    const float* b4 = (const float*)d_in[11];
    const float* w6 = (const float*)d_in[12];
    const float* b6 = (const float*)d_in[13];
    const float* w8 = (const float*)d_in[14];
    const float* b8 = (const float*)d_in[15];
    float* out = (float*)d_out;

    const int Nn = in_sizes[0] / FIN;  // 20000
    const int E = in_sizes[1] / 2;     // 100000
    const int HD = HEADS * HID;        // 2440

    // Compact workspace layout (~257 MB):
    //   [buf1: Nn*HID]  agg1 -> x1 (in-place), then agg2 -> x2 (in-place)
    //   [small: asrc/adst/mbuf/dbuf (Nn*4 each), ebuf (E*4)]
    //   [h: Nn*2440]    ... later overlaid by z[E*512] (extends past h's end)
    float* ws = (float*)d_ws;
    float* buf1 = ws;                              // Nn*HID
    float* asrc = buf1 + (size_t)Nn * HID;         // Nn*4
    float* adst = asrc + (size_t)Nn * HEADS;       // Nn*4
    float* mbuf = adst + (size_t)Nn * HEADS;       // Nn*4
    float* dbuf = mbuf + (size_t)Nn * HEADS;       // Nn*4
    float* ebuf = dbuf + (size_t)Nn * HEADS;       // E*HEADS
    float* h = ebuf + (size_t)E * HEADS;           // Nn*2440
    float* z = h;                                  // E*512 (h + small bufs dead by then)

    dim3 gGemm1((HD + 63) / 64, (Nn + 63) / 64);
    long nodeTot = (long)Nn * HID;
    int fillAggGrid = (int)((nodeTot + 255) / 256);
    int fillSmallGrid = (Nn * HEADS + 255) / 256;
    int edgeThreadGrid = (E + 255) / 256;

    // ---------- GAT layer 1 ----------
    gemm_nt<false><<<gGemm1, 256, 0, stream>>>(x, w0, nullptr, h, Nn, HD, FIN);
    attn_dots<<<Nn, 256, 0, stream>>>(h, att_s0, att_d0, asrc, adst, Nn);
    fill_val<<<fillSmallGrid, 256, 0, stream>>>(mbuf, -INFINITY, Nn * HEADS);
    fill_val<<<fillSmallGrid, 256, 0, stream>>>(dbuf, 0.f, Nn * HEADS);
    fill_val<<<fillAggGrid, 256, 0, stream>>>(buf1, 0.f, nodeTot);
    edge_alpha_max<<<edgeThreadGrid, 256, 0, stream>>>(asrc, adst, ei, ebuf, mbuf, E);
    edge_exp_sum<<<edgeThreadGrid, 256, 0, stream>>>(ei, ebuf, mbuf, dbuf, E);
    edge_message<<<E, 256, 0, stream>>>(h, ei, ebuf, dbuf, buf1, E);
    node_epi<<<fillAggGrid, 256, 0, stream>>>(buf1, b0, buf1, nodeTot);  // x1 in-place

    // ---------- GAT layer 2 ----------
    gemm_nt<false><<<gGemm1, 256, 0, stream>>>(buf1, w2, nullptr, h, Nn, HD, HID);
    attn_dots<<<Nn, 256, 0, stream>>>(h, att_s1, att_d1, asrc, adst, Nn);
    fill_val<<<fillSmallGrid, 256, 0, stream>>>(mbuf, -INFINITY, Nn * HEADS);
    fill_val<<<fillSmallGrid, 256, 0, stream>>>(dbuf, 0.f, Nn * HEADS);
    fill_val<<<fillAggGrid, 256, 0, stream>>>(buf1, 0.f, nodeTot);
    edge_alpha_max<<<edgeThreadGrid, 256, 0, stream>>>(asrc, adst, ei, ebuf, mbuf, E);
    edge_exp_sum<<<edgeThreadGrid, 256, 0, stream>>>(ei, ebuf, mbuf, dbuf, E);
    edge_message<<<E, 256, 0, stream>>>(h, ei, ebuf, dbuf, buf1, E);
    node_epi<<<fillAggGrid, 256, 0, stream>>>(buf1, b2, buf1, nodeTot);  // x2 in-place

    // ---------- edge conv (fused 2-stage) ----------
    edge_conv<<<E, 256, 0, stream>>>(buf1, ei, w4, b4, w6, b6, z, E);

    // ---------- final linear: out = z @ w8^T + b8 ----------
    dim3 gGemm3((NOUT + 63) / 64, (E + 63) / 64);
    gemm_nt<true><<<gGemm3, 256, 0, stream>>>(z, w8, b8, out, E, NOUT, 512);
}

// Round 3
// 2946.688 us; speedup vs baseline: 1.6327x; 1.6327x over previous
//
#include <hip/hip_runtime.h>
#include <hip/hip_bf16.h>
#include <math.h>

#define HEADS 4
#define HID 610
#define FIN 128
#define KER 50
#define NOUT 86
#define NEG_SLOPE 0.2f

// ---------------- utility: fill ----------------
__global__ void fill_val(float* __restrict__ p, float v, long n) {
    long i = (long)blockIdx.x * blockDim.x + threadIdx.x;
    if (i < n) p[i] = v;
}

// ---------------- fp32 tiled GEMM: C[M,N] = A[M,K] * B[N,K]^T (+bias) ----------------
// 128x128 tile, 8x8 per thread, 256 threads. float2 staging (rows only 8B-aligned for K=610).
template <bool BIAS>
__global__ __launch_bounds__(256) void gemm_nt(const float* __restrict__ A,
                                               const float* __restrict__ B,
                                               const float* __restrict__ bias,
                                               float* __restrict__ C,
                                               int M, int N, int K) {
    const int BM = 128, BN = 128, BK = 16;
    __shared__ __align__(16) float As[BK][BM + 4];
    __shared__ __align__(16) float Bs[BK][BN + 4];
    int tid = threadIdx.x;
    int tr = tid / 16, tc = tid % 16;
    int row0 = blockIdx.y * BM;
    int col0 = blockIdx.x * BN;
    float acc[8][8] = {};
    for (int k0 = 0; k0 < K; k0 += BK) {
        // stage A: 128x16 floats = 1024 float2 slots; 4 per thread
#pragma unroll
        for (int qq = 0; qq < 4; qq++) {
            int p = tid + qq * 256;
            int r = p >> 3, c2 = (p & 7) << 1;  // row 0..127, col {0,2,..,14}
            int gr = row0 + r, gc = k0 + c2;
            float2 v = make_float2(0.f, 0.f);
            if (gr < M && gc < K) v = *(const float2*)(A + (long)gr * K + gc);  // K even
            As[c2][r] = v.x;
            As[c2 + 1][r] = v.y;
        }
#pragma unroll
        for (int qq = 0; qq < 4; qq++) {
            int p = tid + qq * 256;
            int r = p >> 3, c2 = (p & 7) << 1;
            int gr = col0 + r, gc = k0 + c2;
            float2 v = make_float2(0.f, 0.f);
            if (gr < N && gc < K) v = *(const float2*)(B + (long)gr * K + gc);
            Bs[c2][r] = v.x;
            Bs[c2 + 1][r] = v.y;
        }
        __syncthreads();
#pragma unroll
        for (int kk = 0; kk < BK; kk++) {
            float a[8], b[8];
            *(float4*)&a[0] = *(const float4*)&As[kk][tr * 8];
            *(float4*)&a[4] = *(const float4*)&As[kk][tr * 8 + 4];
            *(float4*)&b[0] = *(const float4*)&Bs[kk][tc * 8];
            *(float4*)&b[4] = *(const float4*)&Bs[kk][tc * 8 + 4];
#pragma unroll
            for (int i = 0; i < 8; i++)
#pragma unroll
                for (int j = 0; j < 8; j++) acc[i][j] += a[i] * b[j];
        }
        __syncthreads();
    }
#pragma unroll
    for (int i = 0; i < 8; i++) {
        int r = row0 + tr * 8 + i;
        if (r >= M) continue;
#pragma unroll
        for (int j = 0; j < 8; j++) {
            int c = col0 + tc * 8 + j;
            if (c >= N) continue;
            float v = acc[i][j];
            if (BIAS) v += bias[c];
            C[(long)r * N + c] = v;
        }
    }
}

// ---------------- attention dot products per node/head ----------------
__global__ __launch_bounds__(256) void attn_dots(const float* __restrict__ h,
                                                 const float* __restrict__ att_s,
                                                 const float* __restrict__ att_d,
                                                 float* __restrict__ a_src,
                                                 float* __restrict__ a_dst, int Nn) {
    int n = blockIdx.x;
    int head = threadIdx.x >> 6;
    int lane = threadIdx.x & 63;
    const float* hr = h + (long)n * (HEADS * HID) + head * HID;
    const float* as = att_s + head * HID;
    const float* ad = att_d + head * HID;
    float ss = 0.f, sd = 0.f;
    for (int d = lane; d < HID; d += 64) {
        float hv = hr[d];
        ss += hv * as[d];
        sd += hv * ad[d];
    }
    for (int off = 32; off > 0; off >>= 1) {
        ss += __shfl_down(ss, off);
        sd += __shfl_down(sd, off);
    }
    if (lane == 0) {
        a_src[n * HEADS + head] = ss;
        a_dst[n * HEADS + head] = sd;
    }
}

// ---------------- edge alpha + segment max ----------------
__device__ inline void atomicMaxFloat(float* addr, float val) {
    int* ia = (int*)addr;
    int old = __float_as_int(*addr);
    while (__int_as_float(old) < val) {
        int assumed = old;
        old = atomicCAS(ia, assumed, __float_as_int(val));
        if (old == assumed) break;
    }
}

__global__ void edge_alpha_max(const float* __restrict__ a_src, const float* __restrict__ a_dst,
                               const int* __restrict__ ei, float* __restrict__ alpha,
                               float* __restrict__ m, int E) {
    int e = blockIdx.x * blockDim.x + threadIdx.x;
    if (e >= E) return;
    int s = ei[e];
    int d = ei[E + e];
#pragma unroll
    for (int hh = 0; hh < HEADS; hh++) {
        float v = a_src[s * HEADS + hh] + a_dst[d * HEADS + hh];
        v = v >= 0.f ? v : NEG_SLOPE * v;
        alpha[(long)e * HEADS + hh] = v;
        atomicMaxFloat(&m[d * HEADS + hh], v);
    }
}

__global__ void edge_exp_sum(const int* __restrict__ ei, float* __restrict__ alpha,
                             const float* __restrict__ m, float* __restrict__ denom, int E) {
    int e = blockIdx.x * blockDim.x + threadIdx.x;
    if (e >= E) return;
    int d = ei[E + e];
#pragma unroll
    for (int hh = 0; hh < HEADS; hh++) {
        float v = expf(alpha[(long)e * HEADS + hh] - m[d * HEADS + hh]);
        alpha[(long)e * HEADS + hh] = v;
        atomicAdd(&denom[d * HEADS + hh], v);
    }
}

// ---------------- message aggregation ----------------
__global__ __launch_bounds__(256) void edge_message(const float* __restrict__ h,
                                                    const int* __restrict__ ei,
                                                    const float* __restrict__ eexp,
                                                    const float* __restrict__ denom,
                                                    float* __restrict__ agg, int E) {
    int e = blockIdx.x;
    int s = ei[e];
    int d = ei[E + e];
    float coef[HEADS];
#pragma unroll
    for (int hh = 0; hh < HEADS; hh++)
        coef[hh] = 0.25f * eexp[(long)e * HEADS + hh] / (denom[d * HEADS + hh] + 1e-16f);
    const float* hr = h + (long)s * (HEADS * HID);
    float* ar = agg + (long)d * HID;
    for (int dd = threadIdx.x; dd < HID; dd += blockDim.x) {
        float v = coef[0] * hr[dd] + coef[1] * hr[HID + dd] + coef[2] * hr[2 * HID + dd] +
                  coef[3] * hr[3 * HID + dd];
        atomicAdd(&ar[dd], v);
    }
}

// ---------------- node epilogue ----------------
__global__ void node_epi(const float* __restrict__ agg, const float* __restrict__ bias,
                         float* __restrict__ xout, long total) {
    long i = (long)blockIdx.x * blockDim.x + threadIdx.x;
    if (i >= total) return;
    int dcol = (int)(i % HID);
    float v = agg[i] + bias[dcol];
    xout[i] = v > 0.f ? v : 0.f;
}

// ---------------- fused edge conv: wave-per-edge, register sliding windows ----------------
// y staggered in LDS: idx(j) = j + (j>>3)  (breaks stride-8 16-way bank conflict in conv2)
__device__ __forceinline__ int ystag(int j) { return j + (j >> 3); }

__global__ __launch_bounds__(256) void edge_conv(const float* __restrict__ x2,
                                                 const int* __restrict__ ei,
                                                 const float* __restrict__ w4,
                                                 const float* __restrict__ b4,
                                                 const float* __restrict__ w6,
                                                 const float* __restrict__ b6,
                                                 float* __restrict__ z, int E) {
    __shared__ __align__(16) float s[4][628];
    __shared__ __align__(16) float t[4][628];
    __shared__ __align__(16) float y[4][652];  // max ystag(575)=646
    int wave = threadIdx.x >> 6;
    int lane = threadIdx.x & 63;
    int e = blockIdx.x * 4 + wave;
    bool active = (e < E);
    if (active) {
        int sidx = ei[e];
        int didx = ei[E + e];
        const float2* sp = (const float2*)(x2 + (long)sidx * HID);
        const float2* tp = (const float2*)(x2 + (long)didx * HID);
        float2* sl = (float2*)s[wave];
        float2* tl = (float2*)t[wave];
        for (int i = lane; i < HID / 2; i += 64) {
            sl[i] = sp[i];
            tl[i] = tp[i];
        }
    }
    __syncthreads();
    float bb4 = b4[0], bb6 = b6[0];
    if (active) {
        // conv1: 9 outputs per lane, rolling 9-wide window
        int j0 = lane * 9;  // 0..567
        float acc[9], sw[9], tw[9];
#pragma unroll
        for (int i = 0; i < 9; i++) {
            acc[i] = bb4;
            sw[i] = s[wave][j0 + i];
            tw[i] = t[wave][j0 + i];
        }
#pragma unroll
        for (int k = 0; k < KER; k++) {
            float ws_ = w4[k], wt_ = w4[KER + k];
#pragma unroll
            for (int i = 0; i < 9; i++) acc[i] += sw[i] * ws_ + tw[i] * wt_;
#pragma unroll
            for (int i = 0; i < 8; i++) {
                sw[i] = sw[i + 1];
                tw[i] = tw[i + 1];
            }
            sw[8] = s[wave][j0 + 9 + k];  // max 567+9+49=625 < 628
            tw[8] = t[wave][j0 + 9 + k];
        }
#pragma unroll
        for (int i = 0; i < 9; i++)
            y[wave][ystag(j0 + i)] = acc[i] > 0.f ? acc[i] : 0.f;
    }
    __syncthreads();
    if (active) {
        // conv2: 8 outputs per lane, rolling 8-wide window
        int j0 = lane * 8;  // 0..504
        float acc[8], yw[8];
#pragma unroll
        for (int i = 0; i < 8; i++) {
            acc[i] = bb6;
            yw[i] = y[wave][ystag(j0 + i)];
        }
#pragma unroll
        for (int k = 0; k < KER; k++) {
            float wv = w6[k];
#pragma unroll
            for (int i = 0; i < 8; i++) acc[i] += yw[i] * wv;
#pragma unroll
            for (int i = 0; i < 7; i++) yw[i] = yw[i + 1];
            yw[7] = y[wave][ystag(j0 + 8 + k)];  // max ystag(561)=631 < 652
        }
#pragma unroll
        for (int i = 0; i < 8; i++) acc[i] = acc[i] > 0.f ? acc[i] : 0.f;
        float4* zp = (float4*)(z + (long)e * 512 + j0);
        zp[0] = make_float4(acc[0], acc[1], acc[2], acc[3]);
        zp[1] = make_float4(acc[4], acc[5], acc[6], acc[7]);
    }
}

extern "C" void kernel_launch(void* const* d_in, const int* in_sizes, int n_in,
                              void* d_out, int out_size, void* d_ws, size_t ws_size,
                              hipStream_t stream) {
    const float* x = (const float*)d_in[0];
    const int* ei = (const int*)d_in[1];  // int32
    const float* w0 = (const float*)d_in[2];
    const float* b0 = (const float*)d_in[3];
    const float* att_s0 = (const float*)d_in[4];
    const float* att_d0 = (const float*)d_in[5];
    const float* w2 = (const float*)d_in[6];
    const float* b2 = (const float*)d_in[7];
    const float* att_s1 = (const float*)d_in[8];
    const float* att_d1 = (const float*)d_in[9];
    const float* w4 = (const float*)d_in[10];
    const float* b4 = (const float*)d_in[11];
    const float* w6 = (const float*)d_in[12];
    const float* b6 = (const float*)d_in[13];
    const float* w8 = (const float*)d_in[14];
    const float* b8 = (const float*)d_in[15];
    float* out = (float*)d_out;

    const int Nn = in_sizes[0] / FIN;  // 20000
    const int E = in_sizes[1] / 2;     // 100000
    const int HD = HEADS * HID;        // 2440

    float* ws = (float*)d_ws;
    float* buf1 = ws;                              // Nn*HID (agg->x1->agg->x2 in place)
    float* asrc = buf1 + (size_t)Nn * HID;
    float* adst = asrc + (size_t)Nn * HEADS;
    float* mbuf = adst + (size_t)Nn * HEADS;
    float* dbuf = mbuf + (size_t)Nn * HEADS;
    float* ebuf = dbuf + (size_t)Nn * HEADS;       // E*HEADS
    float* h = ebuf + (size_t)E * HEADS;           // Nn*2440
    float* z = h;                                  // E*512 overlays dead h

    dim3 gGemm1((HD + 127) / 128, (Nn + 127) / 128);
    long nodeTot = (long)Nn * HID;
    int fillAggGrid = (int)((nodeTot + 255) / 256);
    int fillSmallGrid = (Nn * HEADS + 255) / 256;
    int edgeThreadGrid = (E + 255) / 256;
    int edgeConvGrid = (E + 3) / 4;

    // ---------- GAT layer 1 ----------
    gemm_nt<false><<<gGemm1, 256, 0, stream>>>(x, w0, nullptr, h, Nn, HD, FIN);
    attn_dots<<<Nn, 256, 0, stream>>>(h, att_s0, att_d0, asrc, adst, Nn);
    fill_val<<<fillSmallGrid, 256, 0, stream>>>(mbuf, -INFINITY, Nn * HEADS);
    fill_val<<<fillSmallGrid, 256, 0, stream>>>(dbuf, 0.f, Nn * HEADS);
    fill_val<<<fillAggGrid, 256, 0, stream>>>(buf1, 0.f, nodeTot);
    edge_alpha_max<<<edgeThreadGrid, 256, 0, stream>>>(asrc, adst, ei, ebuf, mbuf, E);
    edge_exp_sum<<<edgeThreadGrid, 256, 0, stream>>>(ei, ebuf, mbuf, dbuf, E);
    edge_message<<<E, 256, 0, stream>>>(h, ei, ebuf, dbuf, buf1, E);
    node_epi<<<fillAggGrid, 256, 0, stream>>>(buf1, b0, buf1, nodeTot);

    // ---------- GAT layer 2 ----------
    gemm_nt<false><<<gGemm1, 256, 0, stream>>>(buf1, w2, nullptr, h, Nn, HD, HID);
    attn_dots<<<Nn, 256, 0, stream>>>(h, att_s1, att_d1, asrc, adst, Nn);
    fill_val<<<fillSmallGrid, 256, 0, stream>>>(mbuf, -INFINITY, Nn * HEADS);
    fill_val<<<fillSmallGrid, 256, 0, stream>>>(dbuf, 0.f, Nn * HEADS);
    fill_val<<<fillAggGrid, 256, 0, stream>>>(buf1, 0.f, nodeTot);
    edge_alpha_max<<<edgeThreadGrid, 256, 0, stream>>>(asrc, adst, ei, ebuf, mbuf, E);
    edge_exp_sum<<<edgeThreadGrid, 256, 0, stream>>>(ei, ebuf, mbuf, dbuf, E);
    edge_message<<<E, 256, 0, stream>>>(h, ei, ebuf, dbuf, buf1, E);
    node_epi<<<fillAggGrid, 256, 0, stream>>>(buf1, b2, buf1, nodeTot);

    // ---------- edge conv ----------
    edge_conv<<<edgeConvGrid, 256, 0, stream>>>(buf1, ei, w4, b4, w6, b6, z, E);

    // ---------- final linear ----------
    dim3 gGemm3((NOUT + 127) / 128, (E + 127) / 128);
    gemm_nt<true><<<gGemm3, 256, 0, stream>>>(z, w8, b8, out, E, NOUT, 512);
}

// Round 4
// 1590.661 us; speedup vs baseline: 3.0246x; 1.8525x over previous
//
#include <hip/hip_runtime.h>
#include <math.h>

#define HEADS 4
#define HID 610
#define HIDP 640   // K-padded stride for MFMA (mult of 32)
#define FIN 128
#define KER 50
#define NOUT 86
#define NEG_SLOPE 0.2f

typedef short bf8_t __attribute__((ext_vector_type(8)));  // 8 bf16 (4 VGPRs)
typedef float f4_t __attribute__((ext_vector_type(4)));   // MFMA C/D

__device__ __forceinline__ ushort f2bf(float f) {  // RNE fp32->bf16
    unsigned u = __float_as_uint(f);
    unsigned r = (u + 0x7FFFu + ((u >> 16) & 1u)) >> 16;
    return (ushort)r;
}
__device__ __forceinline__ float bf2f(ushort b) { return __uint_as_float(((unsigned)b) << 16); }

// ---------------- utility: fill ----------------
__global__ void fill_val(float* __restrict__ p, float v, long n) {
    long i = (long)blockIdx.x * blockDim.x + threadIdx.x;
    if (i < n) p[i] = v;
}

// ---------------- split fp32 -> bf16 hi/lo with K padding ----------------
__global__ void split_pad(const float* __restrict__ in, ushort* __restrict__ hi,
                          ushort* __restrict__ lo, int R, int K, int Kp) {
    long i = (long)blockIdx.x * blockDim.x + threadIdx.x;
    if (i >= (long)R * Kp) return;
    int r = (int)(i / Kp), c = (int)(i % Kp);
    float v = (c < K) ? in[(long)r * K + c] : 0.f;
    ushort h = f2bf(v);
    hi[i] = h;
    lo[i] = f2bf(v - bf2f(h));
}

// ---------------- split-bf16 MFMA GEMM: C[M,N] = A[M,Kp] * B[N,Kp]^T (+bias) ----------------
// AMODE 0: A fp32 (row stride Kp, zero-padded, 16B-aligned rows), converted in-kernel.
// AMODE 1: A pre-split bf16 hi/lo [M][Kp].
// B always pre-split bf16 hi/lo [N][Kp] (zero-padded).
// 3-term split product: ahi*bhi + alo*bhi + ahi*blo  (error ~2^-17, fp32-equivalent).
template <int AMODE, bool BIAS>
__global__ __launch_bounds__(256) void gemm_mfma(const float* __restrict__ A,
                                                 const ushort* __restrict__ Aghi,
                                                 const ushort* __restrict__ Aglo,
                                                 const ushort* __restrict__ Bghi,
                                                 const ushort* __restrict__ Bglo,
                                                 const float* __restrict__ bias,
                                                 float* __restrict__ C,
                                                 int M, int N, int Kp) {
    __shared__ __align__(16) ushort Ah[128 * 32];
    __shared__ __align__(16) ushort Al[128 * 32];
    __shared__ __align__(16) ushort Bh[128 * 32];
    __shared__ __align__(16) ushort Bl[128 * 32];
    int tid = threadIdx.x;
    int wave = tid >> 6, lane = tid & 63;
    int quad = lane >> 4, l16 = lane & 15;
    int wm = wave & 1, wn = wave >> 1;
    int row0 = blockIdx.y * 128, col0 = blockIdx.x * 128;
    f4_t acc[4][4];
#pragma unroll
    for (int i = 0; i < 4; i++)
#pragma unroll
        for (int j = 0; j < 4; j++) acc[i][j] = (f4_t){0.f, 0.f, 0.f, 0.f};

    for (int k0 = 0; k0 < Kp; k0 += 32) {
        if (AMODE == 0) {
            // 128x32 fp32 tile = 1024 float4 slots, 4/thread; convert to hi/lo bf16
#pragma unroll
            for (int q = 0; q < 4; q++) {
                int p = tid + q * 256;
                int r = p >> 3, c4 = (p & 7) << 2;
                int gr = row0 + r;
                float4 v = make_float4(0.f, 0.f, 0.f, 0.f);
                if (gr < M) v = *(const float4*)(A + (size_t)gr * Kp + k0 + c4);
                ushort4 hv, lv;
                hv.x = f2bf(v.x); lv.x = f2bf(v.x - bf2f(hv.x));
                hv.y = f2bf(v.y); lv.y = f2bf(v.y - bf2f(hv.y));
                hv.z = f2bf(v.z); lv.z = f2bf(v.z - bf2f(hv.z));
                hv.w = f2bf(v.w); lv.w = f2bf(v.w - bf2f(hv.w));
                *(ushort4*)&Ah[r * 32 + c4] = hv;
                *(ushort4*)&Al[r * 32 + c4] = lv;
            }
        } else {
            // 128x32 bf16 tiles hi+lo: 512 16B slots each, 2/thread
#pragma unroll
            for (int q = 0; q < 2; q++) {
                int p = tid + q * 256;
                int r = p >> 2, sg = (p & 3) << 3;
                int gr = row0 + r;
                uint4 vh = make_uint4(0, 0, 0, 0), vl = make_uint4(0, 0, 0, 0);
                if (gr < M) {
                    vh = *(const uint4*)(Aghi + (size_t)gr * Kp + k0 + sg);
                    vl = *(const uint4*)(Aglo + (size_t)gr * Kp + k0 + sg);
                }
                *(uint4*)&Ah[r * 32 + sg] = vh;
                *(uint4*)&Al[r * 32 + sg] = vl;
            }
        }
#pragma unroll
        for (int q = 0; q < 2; q++) {
            int p = tid + q * 256;
            int r = p >> 2, sg = (p & 3) << 3;
            int gr = col0 + r;
            uint4 vh = make_uint4(0, 0, 0, 0), vl = make_uint4(0, 0, 0, 0);
            if (gr < N) {
                vh = *(const uint4*)(Bghi + (size_t)gr * Kp + k0 + sg);
                vl = *(const uint4*)(Bglo + (size_t)gr * Kp + k0 + sg);
            }
            *(uint4*)&Bh[r * 32 + sg] = vh;
            *(uint4*)&Bl[r * 32 + sg] = vl;
        }
        __syncthreads();
        // A frag: A[m=lane&15][k=quad*8+j]; B frag: B[n=lane&15][k=quad*8+j]
        bf8_t ah[4], al[4], bh[4], bl[4];
#pragma unroll
        for (int t = 0; t < 4; t++) {
            int ar = wm * 64 + t * 16 + l16;
            ah[t] = *(const bf8_t*)&Ah[ar * 32 + quad * 8];
            al[t] = *(const bf8_t*)&Al[ar * 32 + quad * 8];
            int br = wn * 64 + t * 16 + l16;
            bh[t] = *(const bf8_t*)&Bh[br * 32 + quad * 8];
            bl[t] = *(const bf8_t*)&Bl[br * 32 + quad * 8];
        }
#pragma unroll
        for (int i = 0; i < 4; i++)
#pragma unroll
            for (int j = 0; j < 4; j++) {
                acc[i][j] = __builtin_amdgcn_mfma_f32_16x16x32_bf16(ah[i], bh[j], acc[i][j], 0, 0, 0);
                acc[i][j] = __builtin_amdgcn_mfma_f32_16x16x32_bf16(al[i], bh[j], acc[i][j], 0, 0, 0);
                acc[i][j] = __builtin_amdgcn_mfma_f32_16x16x32_bf16(ah[i], bl[j], acc[i][j], 0, 0, 0);
            }
        __syncthreads();
    }
    // epilogue: D row(m)=quad*4+reg, col(n)=lane&15
#pragma unroll
    for (int i = 0; i < 4; i++) {
#pragma unroll
        for (int r = 0; r < 4; r++) {
            int grow = row0 + wm * 64 + i * 16 + quad * 4 + r;
            if (grow >= M) continue;
#pragma unroll
            for (int j = 0; j < 4; j++) {
                int gcol = col0 + wn * 64 + j * 16 + l16;
                if (gcol >= N) continue;
                float v = acc[i][j][r];
                if (BIAS) v += bias[gcol];
                C[(size_t)grow * N + gcol] = v;
            }
        }
    }
}

// ---------------- attention dot products per node/head ----------------
__global__ __launch_bounds__(256) void attn_dots(const float* __restrict__ h,
                                                 const float* __restrict__ att_s,
                                                 const float* __restrict__ att_d,
                                                 float* __restrict__ a_src,
                                                 float* __restrict__ a_dst, int Nn) {
    int n = blockIdx.x;
    int head = threadIdx.x >> 6;
    int lane = threadIdx.x & 63;
    const float* hr = h + (long)n * (HEADS * HID) + head * HID;
    const float* as = att_s + head * HID;
    const float* ad = att_d + head * HID;
    float ss = 0.f, sd = 0.f;
    for (int d = lane; d < HID; d += 64) {
        float hv = hr[d];
        ss += hv * as[d];
        sd += hv * ad[d];
    }
    for (int off = 32; off > 0; off >>= 1) {
        ss += __shfl_down(ss, off);
        sd += __shfl_down(sd, off);
    }
    if (lane == 0) {
        a_src[n * HEADS + head] = ss;
        a_dst[n * HEADS + head] = sd;
    }
}

// ---------------- edge alpha + segment max ----------------
__device__ inline void atomicMaxFloat(float* addr, float val) {
    int* ia = (int*)addr;
    int old = __float_as_int(*addr);
    while (__int_as_float(old) < val) {
        int assumed = old;
        old = atomicCAS(ia, assumed, __float_as_int(val));
        if (old == assumed) break;
    }
}

__global__ void edge_alpha_max(const float* __restrict__ a_src, const float* __restrict__ a_dst,
                               const int* __restrict__ ei, float* __restrict__ alpha,
                               float* __restrict__ m, int E) {
    int e = blockIdx.x * blockDim.x + threadIdx.x;
    if (e >= E) return;
    int s = ei[e];
    int d = ei[E + e];
#pragma unroll
    for (int hh = 0; hh < HEADS; hh++) {
        float v = a_src[s * HEADS + hh] + a_dst[d * HEADS + hh];
        v = v >= 0.f ? v : NEG_SLOPE * v;
        alpha[(long)e * HEADS + hh] = v;
        atomicMaxFloat(&m[d * HEADS + hh], v);
    }
}

__global__ void edge_exp_sum(const int* __restrict__ ei, float* __restrict__ alpha,
                             const float* __restrict__ m, float* __restrict__ denom, int E) {
    int e = blockIdx.x * blockDim.x + threadIdx.x;
    if (e >= E) return;
    int d = ei[E + e];
#pragma unroll
    for (int hh = 0; hh < HEADS; hh++) {
        float v = expf(alpha[(long)e * HEADS + hh] - m[d * HEADS + hh]);
        alpha[(long)e * HEADS + hh] = v;
        atomicAdd(&denom[d * HEADS + hh], v);
    }
}

// ---------------- message aggregation (agg row stride HIDP) ----------------
__global__ __launch_bounds__(256) void edge_message(const float* __restrict__ h,
                                                    const int* __restrict__ ei,
                                                    const float* __restrict__ eexp,
                                                    const float* __restrict__ denom,
                                                    float* __restrict__ agg, int E) {
    int e = blockIdx.x;
    int s = ei[e];
    int d = ei[E + e];
    float coef[HEADS];
#pragma unroll
    for (int hh = 0; hh < HEADS; hh++)
        coef[hh] = 0.25f * eexp[(long)e * HEADS + hh] / (denom[d * HEADS + hh] + 1e-16f);
    const float* hr = h + (long)s * (HEADS * HID);
    float* ar = agg + (long)d * HIDP;
    for (int dd = threadIdx.x; dd < HID; dd += blockDim.x) {
        float v = coef[0] * hr[dd] + coef[1] * hr[HID + dd] + coef[2] * hr[2 * HID + dd] +
                  coef[3] * hr[3 * HID + dd];
        atomicAdd(&ar[dd], v);
    }
}

// ---------------- node epilogue (in-place on stride-HIDP buffer, zeroes the K-pad) ------
__global__ void node_epi(float* __restrict__ buf, const float* __restrict__ bias, long total) {
    long i = (long)blockIdx.x * blockDim.x + threadIdx.x;
    if (i >= total) return;
    int col = (int)(i % HIDP);
    float v = 0.f;
    if (col < HID) {
        v = buf[i] + bias[col];
        v = v > 0.f ? v : 0.f;
    }
    buf[i] = v;
}

// ---------------- fused edge conv (x2 stride HIDP) -> z written as bf16 hi/lo ----------
__device__ __forceinline__ int ystag(int j) { return j + (j >> 3); }

__global__ __launch_bounds__(256) void edge_conv(const float* __restrict__ x2,
                                                 const int* __restrict__ ei,
                                                 const float* __restrict__ w4,
                                                 const float* __restrict__ b4,
                                                 const float* __restrict__ w6,
                                                 const float* __restrict__ b6,
                                                 ushort* __restrict__ zhi,
                                                 ushort* __restrict__ zlo, int E) {
    __shared__ __align__(16) float s[4][628];
    __shared__ __align__(16) float t[4][628];
    __shared__ __align__(16) float y[4][652];
    int wave = threadIdx.x >> 6;
    int lane = threadIdx.x & 63;
    int e = blockIdx.x * 4 + wave;
    bool active = (e < E);
    if (active) {
        int sidx = ei[e];
        int didx = ei[E + e];
        const float2* sp = (const float2*)(x2 + (long)sidx * HIDP);
        const float2* tp = (const float2*)(x2 + (long)didx * HIDP);
        float2* sl = (float2*)s[wave];
        float2* tl = (float2*)t[wave];
        for (int i = lane; i < HID / 2; i += 64) {
            sl[i] = sp[i];
            tl[i] = tp[i];
        }
    }
    __syncthreads();
    float bb4 = b4[0], bb6 = b6[0];
    if (active) {
        int j0 = lane * 9;
        float acc[9], sw[9], tw[9];
#pragma unroll
        for (int i = 0; i < 9; i++) {
            acc[i] = bb4;
            sw[i] = s[wave][j0 + i];
            tw[i] = t[wave][j0 + i];
        }
#pragma unroll
        for (int k = 0; k < KER; k++) {
            float ws_ = w4[k], wt_ = w4[KER + k];
#pragma unroll
            for (int i = 0; i < 9; i++) acc[i] += sw[i] * ws_ + tw[i] * wt_;
#pragma unroll
            for (int i = 0; i < 8; i++) {
                sw[i] = sw[i + 1];
                tw[i] = tw[i + 1];
            }
            sw[8] = s[wave][j0 + 9 + k];
            tw[8] = t[wave][j0 + 9 + k];
        }
#pragma unroll
        for (int i = 0; i < 9; i++)
            y[wave][ystag(j0 + i)] = acc[i] > 0.f ? acc[i] : 0.f;
    }
    __syncthreads();
    if (active) {
        int j0 = lane * 8;
        float acc[8], yw[8];
#pragma unroll
        for (int i = 0; i < 8; i++) {
            acc[i] = bb6;
            yw[i] = y[wave][ystag(j0 + i)];
        }
#pragma unroll
        for (int k = 0; k < KER; k++) {
            float wv = w6[k];
#pragma unroll
            for (int i = 0; i < 8; i++) acc[i] += yw[i] * wv;
#pragma unroll
            for (int i = 0; i < 7; i++) yw[i] = yw[i + 1];
            yw[7] = y[wave][ystag(j0 + 8 + k)];
        }
        ushort4 zh0, zh1, zl0, zl1;
        float v;
        v = acc[0] > 0.f ? acc[0] : 0.f; zh0.x = f2bf(v); zl0.x = f2bf(v - bf2f(zh0.x));
        v = acc[1] > 0.f ? acc[1] : 0.f; zh0.y = f2bf(v); zl0.y = f2bf(v - bf2f(zh0.y));
        v = acc[2] > 0.f ? acc[2] : 0.f; zh0.z = f2bf(v); zl0.z = f2bf(v - bf2f(zh0.z));
        v = acc[3] > 0.f ? acc[3] : 0.f; zh0.w = f2bf(v); zl0.w = f2bf(v - bf2f(zh0.w));
        v = acc[4] > 0.f ? acc[4] : 0.f; zh1.x = f2bf(v); zl1.x = f2bf(v - bf2f(zh1.x));
        v = acc[5] > 0.f ? acc[5] : 0.f; zh1.y = f2bf(v); zl1.y = f2bf(v - bf2f(zh1.y));
        v = acc[6] > 0.f ? acc[6] : 0.f; zh1.z = f2bf(v); zl1.z = f2bf(v - bf2f(zh1.z));
        v = acc[7] > 0.f ? acc[7] : 0.f; zh1.w = f2bf(v); zl1.w = f2bf(v - bf2f(zh1.w));
        size_t zo = (size_t)e * 512 + j0;
        *(ushort4*)&zhi[zo] = zh0;
        *(ushort4*)&zhi[zo + 4] = zh1;
        *(ushort4*)&zlo[zo] = zl0;
        *(ushort4*)&zlo[zo + 4] = zl1;
    }
}

extern "C" void kernel_launch(void* const* d_in, const int* in_sizes, int n_in,
                              void* d_out, int out_size, void* d_ws, size_t ws_size,
                              hipStream_t stream) {
    const float* x = (const float*)d_in[0];
    const int* ei = (const int*)d_in[1];  // int32
    const float* w0 = (const float*)d_in[2];
    const float* b0 = (const float*)d_in[3];
    const float* att_s0 = (const float*)d_in[4];
    const float* att_d0 = (const float*)d_in[5];
    const float* w2 = (const float*)d_in[6];
    const float* b2 = (const float*)d_in[7];
    const float* att_s1 = (const float*)d_in[8];
    const float* att_d1 = (const float*)d_in[9];
    const float* w4 = (const float*)d_in[10];
    const float* b4 = (const float*)d_in[11];
    const float* w6 = (const float*)d_in[12];
    const float* b6 = (const float*)d_in[13];
    const float* w8 = (const float*)d_in[14];
    const float* b8 = (const float*)d_in[15];
    float* out = (float*)d_out;

    const int Nn = in_sizes[0] / FIN;  // 20000
    const int E = in_sizes[1] / 2;     // 100000
    const int HD = HEADS * HID;        // 2440

    // ---- workspace layout (floats), total ~257 MB ----
    float* ws = (float*)d_ws;
    size_t o = 0;
    float* buf1 = ws + o; o += (size_t)Nn * HIDP;                 // agg/x1/x2, stride 640
    ushort* w8hi = (ushort*)(ws + o);
    ushort* w8lo = w8hi + (size_t)NOUT * 512; o += (size_t)NOUT * 512;
    float* asrc = ws + o; o += (size_t)Nn * HEADS;
    float* adst = ws + o; o += (size_t)Nn * HEADS;
    float* mbuf = ws + o; o += (size_t)Nn * HEADS;
    float* dbuf = ws + o; o += (size_t)Nn * HEADS;
    float* ebuf = ws + o; o += (size_t)E * HEADS;
    ushort* w0hi = (ushort*)(ws + o);
    ushort* w0lo = w0hi + (size_t)HD * FIN; o += (size_t)HD * FIN;
    ushort* w2hi = (ushort*)(ws + o);
    ushort* w2lo = w2hi + (size_t)HD * HIDP; o += (size_t)HD * HIDP;
    float* h = ws + o;                                            // Nn*2440 fp32
    // z (bf16 hi/lo, E*512 each) overlays asrc..h (all dead by edge_conv time)
    ushort* zhi = (ushort*)asrc;
    ushort* zlo = zhi + (size_t)E * 512;

    long nodeTot = (long)Nn * HIDP;
    int fillAggGrid = (int)((nodeTot + 255) / 256);
    int fillSmallGrid = (Nn * HEADS + 255) / 256;
    int edgeThreadGrid = (E + 255) / 256;
    int edgeConvGrid = (E + 3) / 4;
    dim3 gGemmL((HD + 127) / 128, (Nn + 127) / 128);   // 20 x 157
    dim3 gGemmF((NOUT + 127) / 128, (E + 127) / 128);  // 1 x 782

    // ---- pre-split weights to bf16 hi/lo (K-padded) ----
    split_pad<<<((HD * FIN) + 255) / 256, 256, 0, stream>>>(w0, w0hi, w0lo, HD, FIN, FIN);
    split_pad<<<((HD * HIDP) + 255) / 256, 256, 0, stream>>>(w2, w2hi, w2lo, HD, HID, HIDP);
    split_pad<<<((NOUT * 512) + 255) / 256, 256, 0, stream>>>(w8, w8hi, w8lo, NOUT, 512, 512);

    // ---------- GAT layer 1 ----------
    gemm_mfma<0, false><<<gGemmL, 256, 0, stream>>>(x, nullptr, nullptr, w0hi, w0lo, nullptr,
                                                    h, Nn, HD, FIN);
    attn_dots<<<Nn, 256, 0, stream>>>(h, att_s0, att_d0, asrc, adst, Nn);
    fill_val<<<fillSmallGrid, 256, 0, stream>>>(mbuf, -INFINITY, Nn * HEADS);
    fill_val<<<fillSmallGrid, 256, 0, stream>>>(dbuf, 0.f, Nn * HEADS);
    fill_val<<<fillAggGrid, 256, 0, stream>>>(buf1, 0.f, nodeTot);
    edge_alpha_max<<<edgeThreadGrid, 256, 0, stream>>>(asrc, adst, ei, ebuf, mbuf, E);
    edge_exp_sum<<<edgeThreadGrid, 256, 0, stream>>>(ei, ebuf, mbuf, dbuf, E);
    edge_message<<<E, 256, 0, stream>>>(h, ei, ebuf, dbuf, buf1, E);
    node_epi<<<fillAggGrid, 256, 0, stream>>>(buf1, b0, nodeTot);  // x1 (stride 640, padded)

    // ---------- GAT layer 2 ----------
    gemm_mfma<0, false><<<gGemmL, 256, 0, stream>>>(buf1, nullptr, nullptr, w2hi, w2lo, nullptr,
                                                    h, Nn, HD, HIDP);
    attn_dots<<<Nn, 256, 0, stream>>>(h, att_s1, att_d1, asrc, adst, Nn);
    fill_val<<<fillSmallGrid, 256, 0, stream>>>(mbuf, -INFINITY, Nn * HEADS);
    fill_val<<<fillSmallGrid, 256, 0, stream>>>(dbuf, 0.f, Nn * HEADS);
    fill_val<<<fillAggGrid, 256, 0, stream>>>(buf1, 0.f, nodeTot);
    edge_alpha_max<<<edgeThreadGrid, 256, 0, stream>>>(asrc, adst, ei, ebuf, mbuf, E);
    edge_exp_sum<<<edgeThreadGrid, 256, 0, stream>>>(ei, ebuf, mbuf, dbuf, E);
    edge_message<<<E, 256, 0, stream>>>(h, ei, ebuf, dbuf, buf1, E);
    node_epi<<<fillAggGrid, 256, 0, stream>>>(buf1, b2, nodeTot);  // x2 (stride 640)

    // ---------- edge conv -> z as bf16 hi/lo ----------
    edge_conv<<<edgeConvGrid, 256, 0, stream>>>(buf1, ei, w4, b4, w6, b6, zhi, zlo, E);

    // ---------- final linear: out = z @ w8^T + b8 ----------
    gemm_mfma<1, true><<<gGemmF, 256, 0, stream>>>(nullptr, zhi, zlo, w8hi, w8lo, b8,
                                                   out, E, NOUT, 512);
}

// Round 5
// 1307.771 us; speedup vs baseline: 3.6789x; 1.2163x over previous
//
#include <hip/hip_runtime.h>
#include <math.h>

#define HEADS 4
#define HID 610
#define HIDP 640   // K-padded row stride for MFMA (mult of 32)
#define FIN 128
#define KER 50
#define NOUT 86
#define NEG_SLOPE 0.2f
#define LDA 40     // LDS row stride in ushorts (80B = 20 banks, conflict-free-ish)

typedef short bf8_t __attribute__((ext_vector_type(8)));  // 8 bf16 (4 VGPRs)
typedef float f4_t __attribute__((ext_vector_type(4)));   // MFMA C/D

__device__ __forceinline__ ushort f2bf(float f) {  // RNE fp32->bf16
    unsigned u = __float_as_uint(f);
    unsigned r = (u + 0x7FFFu + ((u >> 16) & 1u)) >> 16;
    return (ushort)r;
}
__device__ __forceinline__ float bf2f(ushort b) { return __uint_as_float(((unsigned)b) << 16); }

// ---------------- utility ----------------
__global__ void fill_val(float* __restrict__ p, float v, long n) {
    long i = (long)blockIdx.x * blockDim.x + threadIdx.x;
    if (i < n) p[i] = v;
}

__global__ void copy_int(const int* __restrict__ a, int* __restrict__ b, int n) {
    int i = blockIdx.x * blockDim.x + threadIdx.x;
    if (i < n) b[i] = a[i];
}

// ---------------- edge sort by dst: histogram / scan / scatter ----------------
__global__ void hist_k(const int* __restrict__ ei, int* __restrict__ hist, int E) {
    int e = blockIdx.x * blockDim.x + threadIdx.x;
    if (e < E) atomicAdd(&hist[ei[E + e]], 1);
}

__global__ __launch_bounds__(1024) void scan_k(const int* __restrict__ hist,
                                               int* __restrict__ base, int Nn) {
    __shared__ int tmp[1024];
    __shared__ int carry;
    if (threadIdx.x == 0) carry = 0;
    __syncthreads();
    for (int c0 = 0; c0 < Nn; c0 += 1024) {
        int i = c0 + threadIdx.x;
        int v = (i < Nn) ? hist[i] : 0;
        tmp[threadIdx.x] = v;
        __syncthreads();
        for (int off = 1; off < 1024; off <<= 1) {
            int t = (threadIdx.x >= off) ? tmp[threadIdx.x - off] : 0;
            __syncthreads();
            tmp[threadIdx.x] += t;
            __syncthreads();
        }
        if (i < Nn) base[i] = carry + tmp[threadIdx.x] - v;  // exclusive
        __syncthreads();
        if (threadIdx.x == 1023) carry += tmp[1023];
        __syncthreads();
    }
    if (threadIdx.x == 0) base[Nn] = carry;
}

__global__ void scatter_k(const int* __restrict__ ei, int* __restrict__ cursor,
                          int* __restrict__ esrc, int E) {
    int e = blockIdx.x * blockDim.x + threadIdx.x;
    if (e >= E) return;
    int d = ei[E + e];
    int pos = atomicAdd(&cursor[d], 1);
    esrc[pos] = ei[e];
}

// ---------------- split fp32 -> bf16 hi/lo with K padding ----------------
__global__ void split_pad(const float* __restrict__ in, ushort* __restrict__ hi,
                          ushort* __restrict__ lo, int R, int K, int Kp) {
    long i = (long)blockIdx.x * blockDim.x + threadIdx.x;
    if (i >= (long)R * Kp) return;
    int r = (int)(i / Kp), c = (int)(i % Kp);
    float v = (c < K) ? in[(long)r * K + c] : 0.f;
    ushort h = f2bf(v);
    hi[i] = h;
    lo[i] = f2bf(v - bf2f(h));
}

// ---------------- split-bf16 MFMA GEMM: C[M,N] = A[M,Kp] * B[N,Kp]^T (+bias) ----------------
template <int AMODE, bool BIAS>
__global__ __launch_bounds__(256) void gemm_mfma(const float* __restrict__ A,
                                                 const ushort* __restrict__ Aghi,
                                                 const ushort* __restrict__ Aglo,
                                                 const ushort* __restrict__ Bghi,
                                                 const ushort* __restrict__ Bglo,
                                                 const float* __restrict__ bias,
                                                 float* __restrict__ C,
                                                 int M, int N, int Kp) {
    __shared__ __align__(16) ushort Ah[128 * LDA];
    __shared__ __align__(16) ushort Al[128 * LDA];
    __shared__ __align__(16) ushort Bh[128 * LDA];
    __shared__ __align__(16) ushort Bl[128 * LDA];
    int tid = threadIdx.x;
    int wave = tid >> 6, lane = tid & 63;
    int quad = lane >> 4, l16 = lane & 15;
    int wm = wave & 1, wn = wave >> 1;
    int row0 = blockIdx.y * 128, col0 = blockIdx.x * 128;
    f4_t acc[4][4];
#pragma unroll
    for (int i = 0; i < 4; i++)
#pragma unroll
        for (int j = 0; j < 4; j++) acc[i][j] = (f4_t){0.f, 0.f, 0.f, 0.f};

    for (int k0 = 0; k0 < Kp; k0 += 32) {
        if (AMODE == 0) {
#pragma unroll
            for (int q = 0; q < 4; q++) {
                int p = tid + q * 256;
                int r = p >> 3, c4 = (p & 7) << 2;
                int gr = row0 + r;
                float4 v = make_float4(0.f, 0.f, 0.f, 0.f);
                if (gr < M) v = *(const float4*)(A + (size_t)gr * Kp + k0 + c4);
                ushort4 hv, lv;
                hv.x = f2bf(v.x); lv.x = f2bf(v.x - bf2f(hv.x));
                hv.y = f2bf(v.y); lv.y = f2bf(v.y - bf2f(hv.y));
                hv.z = f2bf(v.z); lv.z = f2bf(v.z - bf2f(hv.z));
                hv.w = f2bf(v.w); lv.w = f2bf(v.w - bf2f(hv.w));
                *(ushort4*)&Ah[r * LDA + c4] = hv;
                *(ushort4*)&Al[r * LDA + c4] = lv;
            }
        } else {
#pragma unroll
            for (int q = 0; q < 2; q++) {
                int p = tid + q * 256;
                int r = p >> 2, sg = (p & 3) << 3;
                int gr = row0 + r;
                uint4 vh = make_uint4(0, 0, 0, 0), vl = make_uint4(0, 0, 0, 0);
                if (gr < M) {
                    vh = *(const uint4*)(Aghi + (size_t)gr * Kp + k0 + sg);
                    vl = *(const uint4*)(Aglo + (size_t)gr * Kp + k0 + sg);
                }
                *(uint4*)&Ah[r * LDA + sg] = vh;
                *(uint4*)&Al[r * LDA + sg] = vl;
            }
        }
#pragma unroll
        for (int q = 0; q < 2; q++) {
            int p = tid + q * 256;
            int r = p >> 2, sg = (p & 3) << 3;
            int gr = col0 + r;
            uint4 vh = make_uint4(0, 0, 0, 0), vl = make_uint4(0, 0, 0, 0);
            if (gr < N) {
                vh = *(const uint4*)(Bghi + (size_t)gr * Kp + k0 + sg);
                vl = *(const uint4*)(Bglo + (size_t)gr * Kp + k0 + sg);
            }
            *(uint4*)&Bh[r * LDA + sg] = vh;
            *(uint4*)&Bl[r * LDA + sg] = vl;
        }
        __syncthreads();
        bf8_t ah[4], al[4], bh[4], bl[4];
#pragma unroll
        for (int t = 0; t < 4; t++) {
            int ar = wm * 64 + t * 16 + l16;
            ah[t] = *(const bf8_t*)&Ah[ar * LDA + quad * 8];
            al[t] = *(const bf8_t*)&Al[ar * LDA + quad * 8];
            int br = wn * 64 + t * 16 + l16;
            bh[t] = *(const bf8_t*)&Bh[br * LDA + quad * 8];
            bl[t] = *(const bf8_t*)&Bl[br * LDA + quad * 8];
        }
#pragma unroll
        for (int i = 0; i < 4; i++)
#pragma unroll
            for (int j = 0; j < 4; j++) {
                acc[i][j] = __builtin_amdgcn_mfma_f32_16x16x32_bf16(ah[i], bh[j], acc[i][j], 0, 0, 0);
                acc[i][j] = __builtin_amdgcn_mfma_f32_16x16x32_bf16(al[i], bh[j], acc[i][j], 0, 0, 0);
                acc[i][j] = __builtin_amdgcn_mfma_f32_16x16x32_bf16(ah[i], bl[j], acc[i][j], 0, 0, 0);
            }
        __syncthreads();
    }
#pragma unroll
    for (int i = 0; i < 4; i++) {
#pragma unroll
        for (int r = 0; r < 4; r++) {
            int grow = row0 + wm * 64 + i * 16 + quad * 4 + r;
            if (grow >= M) continue;
#pragma unroll
            for (int j = 0; j < 4; j++) {
                int gcol = col0 + wn * 64 + j * 16 + l16;
                if (gcol >= N) continue;
                float v = acc[i][j][r];
                if (BIAS) v += bias[gcol];
                C[(size_t)grow * N + gcol] = v;
            }
        }
    }
}

// ---------------- attention dot products per node/head ----------------
__global__ __launch_bounds__(256) void attn_dots(const float* __restrict__ h,
                                                 const float* __restrict__ att_s,
                                                 const float* __restrict__ att_d,
                                                 float* __restrict__ a_src,
                                                 float* __restrict__ a_dst, int Nn) {
    int n = blockIdx.x;
    int head = threadIdx.x >> 6;
    int lane = threadIdx.x & 63;
    const float2* hr = (const float2*)(h + (long)n * (HEADS * HID) + head * HID);
    const float2* as = (const float2*)(att_s + head * HID);
    const float2* ad = (const float2*)(att_d + head * HID);
    float ss = 0.f, sd = 0.f;
    for (int d = lane; d < HID / 2; d += 64) {
        float2 hv = hr[d], av = as[d], dv = ad[d];
        ss += hv.x * av.x + hv.y * av.y;
        sd += hv.x * dv.x + hv.y * dv.y;
    }
    for (int off = 32; off > 0; off >>= 1) {
        ss += __shfl_down(ss, off);
        sd += __shfl_down(sd, off);
    }
    if (lane == 0) {
        a_src[n * HEADS + head] = ss;
        a_dst[n * HEADS + head] = sd;
    }
}

// ---------------- per-dst-node softmax + aggregation (atomic-free, CSR) ----------------
// One wave per destination node. Fuses: leaky-relu, segment max/sum, softmax,
// weighted message sum over heads, head-mean (0.25), bias, relu, K-pad zeroing.
__global__ __launch_bounds__(256) void node_aggregate(
    const float* __restrict__ h, const float* __restrict__ asrc,
    const float* __restrict__ adst, const int* __restrict__ base,
    const int* __restrict__ esrc, const float* __restrict__ bias,
    float* __restrict__ xout, int Nn) {
    int wave = threadIdx.x >> 6, lane = threadIdx.x & 63;
    int n = blockIdx.x * 4 + wave;
    if (n >= Nn) return;
    int b0 = base[n], deg = base[n + 1] - b0;
    float ad[HEADS];
#pragma unroll
    for (int hh = 0; hh < HEADS; hh++) ad[hh] = adst[n * HEADS + hh];
    // pass A: per-head max
    float m[HEADS] = {-INFINITY, -INFINITY, -INFINITY, -INFINITY};
    for (int eb = 0; eb < deg; eb += 64) {
        int i = eb + lane;
        if (i < deg) {
            int s = esrc[b0 + i];
#pragma unroll
            for (int hh = 0; hh < HEADS; hh++) {
                float v = asrc[s * HEADS + hh] + ad[hh];
                v = v >= 0.f ? v : NEG_SLOPE * v;
                m[hh] = fmaxf(m[hh], v);
            }
        }
    }
#pragma unroll
    for (int off = 32; off > 0; off >>= 1)
#pragma unroll
        for (int hh = 0; hh < HEADS; hh++) m[hh] = fmaxf(m[hh], __shfl_xor(m[hh], off));
    // pass B: denom
    float sden[HEADS] = {0.f, 0.f, 0.f, 0.f};
    for (int eb = 0; eb < deg; eb += 64) {
        int i = eb + lane;
        if (i < deg) {
            int s = esrc[b0 + i];
#pragma unroll
            for (int hh = 0; hh < HEADS; hh++) {
                float v = asrc[s * HEADS + hh] + ad[hh];
                v = v >= 0.f ? v : NEG_SLOPE * v;
                sden[hh] += expf(v - m[hh]);
            }
        }
    }
#pragma unroll
    for (int off = 32; off > 0; off >>= 1)
#pragma unroll
        for (int hh = 0; hh < HEADS; hh++) sden[hh] += __shfl_xor(sden[hh], off);
    float inv[HEADS];
#pragma unroll
    for (int hh = 0; hh < HEADS; hh++) inv[hh] = 0.25f / (sden[hh] + 1e-16f);
    // pass C: weighted aggregation
    float acc0[10] = {}, acc1[10] = {}, acc2[10] = {}, acc3[10] = {};
    for (int eb = 0; eb < deg; eb += 64) {
        int i = eb + lane;
        int sreg = 0;
        float coef[HEADS] = {0.f, 0.f, 0.f, 0.f};
        if (i < deg) {
            sreg = esrc[b0 + i];
#pragma unroll
            for (int hh = 0; hh < HEADS; hh++) {
                float v = asrc[sreg * HEADS + hh] + ad[hh];
                v = v >= 0.f ? v : NEG_SLOPE * v;
                coef[hh] = expf(v - m[hh]) * inv[hh];
            }
        }
        int cnt = deg - eb < 64 ? deg - eb : 64;
        for (int j = 0; j < cnt; j++) {
            int s = __shfl(sreg, j);
            float c0 = __shfl(coef[0], j), c1 = __shfl(coef[1], j);
            float c2 = __shfl(coef[2], j), c3 = __shfl(coef[3], j);
            const float* hr = h + (size_t)s * (HEADS * HID);
#pragma unroll
            for (int t = 0; t < 10; t++) {
                int d = lane + t * 64;
                if (d < HID) {
                    acc0[t] = fmaf(c0, hr[d], acc0[t]);
                    acc1[t] = fmaf(c1, hr[HID + d], acc1[t]);
                    acc2[t] = fmaf(c2, hr[2 * HID + d], acc2[t]);
                    acc3[t] = fmaf(c3, hr[3 * HID + d], acc3[t]);
                }
            }
        }
    }
    float* orow = xout + (size_t)n * HIDP;
#pragma unroll
    for (int t = 0; t < 10; t++) {
        int d = lane + t * 64;
        if (d < HID) {
            float v = acc0[t] + acc1[t] + acc2[t] + acc3[t] + bias[d];
            orow[d] = v > 0.f ? v : 0.f;
        }
    }
    for (int d = HID + lane; d < HIDP; d += 64) orow[d] = 0.f;
}

// ---------------- fused edge conv (x2 stride HIDP) -> z written as bf16 hi/lo ----------
__device__ __forceinline__ int ystag(int j) { return j + (j >> 3); }

__global__ __launch_bounds__(256) void edge_conv(const float* __restrict__ x2,
                                                 const int* __restrict__ ei,
                                                 const float* __restrict__ w4,
                                                 const float* __restrict__ b4,
                                                 const float* __restrict__ w6,
                                                 const float* __restrict__ b6,
                                                 ushort* __restrict__ zhi,
                                                 ushort* __restrict__ zlo, int E) {
    __shared__ __align__(16) float s[4][628];
    __shared__ __align__(16) float t[4][628];
    __shared__ __align__(16) float y[4][652];
    int wave = threadIdx.x >> 6;
    int lane = threadIdx.x & 63;
    int e = blockIdx.x * 4 + wave;
    bool active = (e < E);
    if (active) {
        int sidx = ei[e];
        int didx = ei[E + e];
        const float2* sp = (const float2*)(x2 + (long)sidx * HIDP);
        const float2* tp = (const float2*)(x2 + (long)didx * HIDP);
        float2* sl = (float2*)s[wave];
        float2* tl = (float2*)t[wave];
        for (int i = lane; i < HID / 2; i += 64) {
            sl[i] = sp[i];
            tl[i] = tp[i];
        }
    }
    __syncthreads();
    float bb4 = b4[0], bb6 = b6[0];
    if (active) {
        int j0 = lane * 9;
        float acc[9], sw[9], tw[9];
#pragma unroll
        for (int i = 0; i < 9; i++) {
            acc[i] = bb4;
            sw[i] = s[wave][j0 + i];
            tw[i] = t[wave][j0 + i];
        }
#pragma unroll
        for (int k = 0; k < KER; k++) {
            float ws_ = w4[k], wt_ = w4[KER + k];
#pragma unroll
            for (int i = 0; i < 9; i++) acc[i] += sw[i] * ws_ + tw[i] * wt_;
#pragma unroll
            for (int i = 0; i < 8; i++) {
                sw[i] = sw[i + 1];
                tw[i] = tw[i + 1];
            }
            sw[8] = s[wave][j0 + 9 + k];
            tw[8] = t[wave][j0 + 9 + k];
        }
#pragma unroll
        for (int i = 0; i < 9; i++)
            y[wave][ystag(j0 + i)] = acc[i] > 0.f ? acc[i] : 0.f;
    }
    __syncthreads();
    if (active) {
        int j0 = lane * 8;
        float acc[8], yw[8];
#pragma unroll
        for (int i = 0; i < 8; i++) {
            acc[i] = bb6;
            yw[i] = y[wave][ystag(j0 + i)];
        }
#pragma unroll
        for (int k = 0; k < KER; k++) {
            float wv = w6[k];
#pragma unroll
            for (int i = 0; i < 8; i++) acc[i] += yw[i] * wv;
#pragma unroll
            for (int i = 0; i < 7; i++) yw[i] = yw[i + 1];
            yw[7] = y[wave][ystag(j0 + 8 + k)];
        }
        ushort4 zh0, zh1, zl0, zl1;
        float v;
        v = acc[0] > 0.f ? acc[0] : 0.f; zh0.x = f2bf(v); zl0.x = f2bf(v - bf2f(zh0.x));
        v = acc[1] > 0.f ? acc[1] : 0.f; zh0.y = f2bf(v); zl0.y = f2bf(v - bf2f(zh0.y));
        v = acc[2] > 0.f ? acc[2] : 0.f; zh0.z = f2bf(v); zl0.z = f2bf(v - bf2f(zh0.z));
        v = acc[3] > 0.f ? acc[3] : 0.f; zh0.w = f2bf(v); zl0.w = f2bf(v - bf2f(zh0.w));
        v = acc[4] > 0.f ? acc[4] : 0.f; zh1.x = f2bf(v); zl1.x = f2bf(v - bf2f(zh1.x));
        v = acc[5] > 0.f ? acc[5] : 0.f; zh1.y = f2bf(v); zl1.y = f2bf(v - bf2f(zh1.y));
        v = acc[6] > 0.f ? acc[6] : 0.f; zh1.z = f2bf(v); zl1.z = f2bf(v - bf2f(zh1.z));
        v = acc[7] > 0.f ? acc[7] : 0.f; zh1.w = f2bf(v); zl1.w = f2bf(v - bf2f(zh1.w));
        size_t zo = (size_t)e * 512 + j0;
        *(ushort4*)&zhi[zo] = zh0;
        *(ushort4*)&zhi[zo + 4] = zh1;
        *(ushort4*)&zlo[zo] = zl0;
        *(ushort4*)&zlo[zo + 4] = zl1;
    }
}

extern "C" void kernel_launch(void* const* d_in, const int* in_sizes, int n_in,
                              void* d_out, int out_size, void* d_ws, size_t ws_size,
                              hipStream_t stream) {
    const float* x = (const float*)d_in[0];
    const int* ei = (const int*)d_in[1];  // int32
    const float* w0 = (const float*)d_in[2];
    const float* b0 = (const float*)d_in[3];
    const float* att_s0 = (const float*)d_in[4];
    const float* att_d0 = (const float*)d_in[5];
    const float* w2 = (const float*)d_in[6];
    const float* b2 = (const float*)d_in[7];
    const float* att_s1 = (const float*)d_in[8];
    const float* att_d1 = (const float*)d_in[9];
    const float* w4 = (const float*)d_in[10];
    const float* b4 = (const float*)d_in[11];
    const float* w6 = (const float*)d_in[12];
    const float* b6 = (const float*)d_in[13];
    const float* w8 = (const float*)d_in[14];
    const float* b8 = (const float*)d_in[15];
    float* out = (float*)d_out;

    const int Nn = in_sizes[0] / FIN;  // 20000
    const int E = in_sizes[1] / 2;     // 100000
    const int HD = HEADS * HID;        // 2440

    // ---- workspace layout (floats), watermark ~256 MB (<= proven-safe R3/R4 level) ----
    float* ws = (float*)d_ws;
    size_t o = 0;
    float* buf1 = ws + o; o += (size_t)Nn * HIDP;                 // x1/x2, stride 640 (live thru conv)
    ushort* w8hi = (ushort*)(ws + o);
    ushort* w8lo = w8hi + (size_t)NOUT * 512; o += (size_t)NOUT * 512;
    // z (bf16 hi/lo) overlays everything from here on (sort/attn/h all dead by conv time)
    ushort* zhi = (ushort*)(ws + o);
    ushort* zlo = zhi + (size_t)E * 512;
    int* base = (int*)(ws + o); o += (size_t)Nn + 4;
    int* cursor = (int*)(ws + o); o += (size_t)Nn;                // also hist
    int* esrc = (int*)(ws + o); o += (size_t)E;
    float* asrc = ws + o; o += (size_t)Nn * HEADS;
    float* adst = ws + o; o += (size_t)Nn * HEADS;
    ushort* w0hi = (ushort*)(ws + o);
    ushort* w0lo = w0hi + (size_t)HD * FIN; o += (size_t)HD * FIN;
    ushort* w2hi = (ushort*)(ws + o);
    ushort* w2lo = w2hi + (size_t)HD * HIDP; o += (size_t)HD * HIDP;
    float* h = ws + o;                                            // Nn*2440 fp32

    int edgeGrid = (E + 255) / 256;
    int nodeWaveGrid = (Nn + 3) / 4;
    int edgeConvGrid = (E + 3) / 4;
    dim3 gGemmL((HD + 127) / 128, (Nn + 127) / 128);   // 20 x 157
    dim3 gGemmF((NOUT + 127) / 128, (E + 127) / 128);  // 1 x 782

    // ---- one-time: weight split + edge sort by dst ----
    split_pad<<<((HD * FIN) + 255) / 256, 256, 0, stream>>>(w0, w0hi, w0lo, HD, FIN, FIN);
    split_pad<<<((HD * HIDP) + 255) / 256, 256, 0, stream>>>(w2, w2hi, w2lo, HD, HID, HIDP);
    split_pad<<<((NOUT * 512) + 255) / 256, 256, 0, stream>>>(w8, w8hi, w8lo, NOUT, 512, 512);
    fill_val<<<(Nn + 255) / 256, 256, 0, stream>>>((float*)cursor, 0.f, Nn);  // hist=0
    hist_k<<<edgeGrid, 256, 0, stream>>>(ei, cursor, E);
    scan_k<<<1, 1024, 0, stream>>>(cursor, base, Nn);
    copy_int<<<(Nn + 255) / 256, 256, 0, stream>>>(base, cursor, Nn);
    scatter_k<<<edgeGrid, 256, 0, stream>>>(ei, cursor, esrc, E);

    // ---------- GAT layer 1 ----------
    gemm_mfma<0, false><<<gGemmL, 256, 0, stream>>>(x, nullptr, nullptr, w0hi, w0lo, nullptr,
                                                    h, Nn, HD, FIN);
    attn_dots<<<Nn, 256, 0, stream>>>(h, att_s0, att_d0, asrc, adst, Nn);
    node_aggregate<<<nodeWaveGrid, 256, 0, stream>>>(h, asrc, adst, base, esrc, b0, buf1, Nn);

    // ---------- GAT layer 2 ----------
    gemm_mfma<0, false><<<gGemmL, 256, 0, stream>>>(buf1, nullptr, nullptr, w2hi, w2lo, nullptr,
                                                    h, Nn, HD, HIDP);
    attn_dots<<<Nn, 256, 0, stream>>>(h, att_s1, att_d1, asrc, adst, Nn);
    node_aggregate<<<nodeWaveGrid, 256, 0, stream>>>(h, asrc, adst, base, esrc, b2, buf1, Nn);

    // ---------- edge conv -> z as bf16 hi/lo ----------
    edge_conv<<<edgeConvGrid, 256, 0, stream>>>(buf1, ei, w4, b4, w6, b6, zhi, zlo, E);

    // ---------- final linear: out = z @ w8^T + b8 ----------
    gemm_mfma<1, true><<<gGemmF, 256, 0, stream>>>(nullptr, zhi, zlo, w8hi, w8lo, b8,
                                                   out, E, NOUT, 512);
}

// Round 6
// 1169.341 us; speedup vs baseline: 4.1144x; 1.1184x over previous
//
#include <hip/hip_runtime.h>
#include <math.h>

#define HEADS 4
#define HID 610
#define HIDP 640   // K-padded row stride for MFMA (mult of 32)
#define FIN 128
#define KER 50
#define NOUT 86
#define NEG_SLOPE 0.2f

typedef short bf8_t __attribute__((ext_vector_type(8)));  // 8 bf16 (4 VGPRs)
typedef float f4_t __attribute__((ext_vector_type(4)));   // MFMA C/D

__device__ __forceinline__ ushort f2bf(float f) {  // RNE fp32->bf16
    unsigned u = __float_as_uint(f);
    unsigned r = (u + 0x7FFFu + ((u >> 16) & 1u)) >> 16;
    return (ushort)r;
}
__device__ __forceinline__ float bf2f(ushort b) { return __uint_as_float(((unsigned)b) << 16); }

// ---------------- utility ----------------
__global__ void fill_val(float* __restrict__ p, float v, long n) {
    long i = (long)blockIdx.x * blockDim.x + threadIdx.x;
    if (i < n) p[i] = v;
}

__global__ void copy_int(const int* __restrict__ a, int* __restrict__ b, int n) {
    int i = blockIdx.x * blockDim.x + threadIdx.x;
    if (i < n) b[i] = a[i];
}

// ---------------- edge sort by dst: histogram / scan / scatter ----------------
__global__ void hist_k(const int* __restrict__ ei, int* __restrict__ hist, int E) {
    int e = blockIdx.x * blockDim.x + threadIdx.x;
    if (e < E) atomicAdd(&hist[ei[E + e]], 1);
}

__global__ __launch_bounds__(1024) void scan_k(const int* __restrict__ hist,
                                               int* __restrict__ base, int Nn) {
    __shared__ int tmp[1024];
    __shared__ int carry;
    if (threadIdx.x == 0) carry = 0;
    __syncthreads();
    for (int c0 = 0; c0 < Nn; c0 += 1024) {
        int i = c0 + threadIdx.x;
        int v = (i < Nn) ? hist[i] : 0;
        tmp[threadIdx.x] = v;
        __syncthreads();
        for (int off = 1; off < 1024; off <<= 1) {
            int t = (threadIdx.x >= off) ? tmp[threadIdx.x - off] : 0;
            __syncthreads();
            tmp[threadIdx.x] += t;
            __syncthreads();
        }
        if (i < Nn) base[i] = carry + tmp[threadIdx.x] - v;  // exclusive
        __syncthreads();
        if (threadIdx.x == 1023) carry += tmp[1023];
        __syncthreads();
    }
    if (threadIdx.x == 0) base[Nn] = carry;
}

__global__ void scatter_k(const int* __restrict__ ei, int* __restrict__ cursor,
                          int* __restrict__ esrc, int E) {
    int e = blockIdx.x * blockDim.x + threadIdx.x;
    if (e >= E) return;
    int d = ei[E + e];
    int pos = atomicAdd(&cursor[d], 1);
    esrc[pos] = ei[e];
}

// ---------------- split fp32 -> bf16 hi/lo with K padding ----------------
__global__ void split_pad(const float* __restrict__ in, ushort* __restrict__ hi,
                          ushort* __restrict__ lo, int R, int K, int Kp) {
    long i = (long)blockIdx.x * blockDim.x + threadIdx.x;
    if (i >= (long)R * Kp) return;
    int r = (int)(i / Kp), c = (int)(i % Kp);
    float v = (c < K) ? in[(long)r * K + c] : 0.f;
    ushort h = f2bf(v);
    hi[i] = h;
    lo[i] = f2bf(v - bf2f(h));
}

// ---------------- split-bf16 MFMA GEMM: C[M,N] = A[M,Kp] * B[N,Kp]^T (+bias) ----------------
// LDS layout: rows of 32 ushorts (64B = 4 chunks of 16B); chunk c of row r stored at
// chunk position c ^ ((r>>1)&3). Staging writes stay contiguous within each row;
// fragment ds_read_b128 lands exactly 2 lanes/bank (free). Register prefetch
// double-buffers the global staging loads across the MFMA loop.
template <int AMODE, bool BIAS>
__global__ __launch_bounds__(256) void gemm_mfma(const float* __restrict__ A,
                                                 const ushort* __restrict__ Aghi,
                                                 const ushort* __restrict__ Aglo,
                                                 const ushort* __restrict__ Bghi,
                                                 const ushort* __restrict__ Bglo,
                                                 const float* __restrict__ bias,
                                                 float* __restrict__ C,
                                                 int M, int N, int Kp) {
    __shared__ __align__(16) ushort Ah[128 * 32];
    __shared__ __align__(16) ushort Al[128 * 32];
    __shared__ __align__(16) ushort Bh[128 * 32];
    __shared__ __align__(16) ushort Bl[128 * 32];
    int tid = threadIdx.x;
    int wave = tid >> 6, lane = tid & 63;
    int quad = lane >> 4, l16 = lane & 15;
    int wm = wave & 1, wn = wave >> 1;
    int row0 = blockIdx.y * 128, col0 = blockIdx.x * 128;

    float4 pa0[4];
    uint4 pah[2], pal[2], pbh[2], pbl[2];

    auto loadA = [&](int k0) {
        if (AMODE == 0) {
#pragma unroll
            for (int q = 0; q < 4; q++) {
                int p = tid + q * 256;
                int r = p >> 3, c4 = (p & 7) << 2;
                int gr = row0 + r;
                pa0[q] = (gr < M) ? *(const float4*)(A + (size_t)gr * Kp + k0 + c4)
                                  : make_float4(0.f, 0.f, 0.f, 0.f);
            }
        } else {
#pragma unroll
            for (int q = 0; q < 2; q++) {
                int p = tid + q * 256;
                int r = p >> 2, c = p & 3;
                int gr = row0 + r;
                if (gr < M) {
                    pah[q] = *(const uint4*)(Aghi + (size_t)gr * Kp + k0 + c * 8);
                    pal[q] = *(const uint4*)(Aglo + (size_t)gr * Kp + k0 + c * 8);
                } else {
                    pah[q] = make_uint4(0, 0, 0, 0);
                    pal[q] = make_uint4(0, 0, 0, 0);
                }
            }
        }
    };
    auto loadB = [&](int k0) {
#pragma unroll
        for (int q = 0; q < 2; q++) {
            int p = tid + q * 256;
            int r = p >> 2, c = p & 3;
            int gr = col0 + r;
            if (gr < N) {
                pbh[q] = *(const uint4*)(Bghi + (size_t)gr * Kp + k0 + c * 8);
                pbl[q] = *(const uint4*)(Bglo + (size_t)gr * Kp + k0 + c * 8);
            } else {
                pbh[q] = make_uint4(0, 0, 0, 0);
                pbl[q] = make_uint4(0, 0, 0, 0);
            }
        }
    };
    auto writeLDS = [&]() {
        if (AMODE == 0) {
#pragma unroll
            for (int q = 0; q < 4; q++) {
                int p = tid + q * 256;
                int r = p >> 3, m = p & 7;
                int pos = r * 32 + ((((m >> 1)) ^ ((r >> 1) & 3)) << 3) + ((m & 1) << 2);
                float4 v = pa0[q];
                ushort4 hv, lv;
                hv.x = f2bf(v.x); lv.x = f2bf(v.x - bf2f(hv.x));
                hv.y = f2bf(v.y); lv.y = f2bf(v.y - bf2f(hv.y));
                hv.z = f2bf(v.z); lv.z = f2bf(v.z - bf2f(hv.z));
                hv.w = f2bf(v.w); lv.w = f2bf(v.w - bf2f(hv.w));
                *(ushort4*)&Ah[pos] = hv;
                *(ushort4*)&Al[pos] = lv;
            }
        } else {
#pragma unroll
            for (int q = 0; q < 2; q++) {
                int p = tid + q * 256;
                int r = p >> 2, c = p & 3;
                int pos = r * 32 + ((c ^ ((r >> 1) & 3)) << 3);
                *(uint4*)&Ah[pos] = pah[q];
                *(uint4*)&Al[pos] = pal[q];
            }
        }
#pragma unroll
        for (int q = 0; q < 2; q++) {
            int p = tid + q * 256;
            int r = p >> 2, c = p & 3;
            int pos = r * 32 + ((c ^ ((r >> 1) & 3)) << 3);
            *(uint4*)&Bh[pos] = pbh[q];
            *(uint4*)&Bl[pos] = pbl[q];
        }
    };

    f4_t acc[4][4];
#pragma unroll
    for (int i = 0; i < 4; i++)
#pragma unroll
        for (int j = 0; j < 4; j++) acc[i][j] = (f4_t){0.f, 0.f, 0.f, 0.f};

    loadA(0);
    loadB(0);
    int sw = (quad ^ ((l16 >> 1) & 3)) << 3;
    for (int k0 = 0; k0 < Kp; k0 += 32) {
        __syncthreads();
        writeLDS();
        __syncthreads();
        if (k0 + 32 < Kp) {
            loadA(k0 + 32);
            loadB(k0 + 32);
        }
        bf8_t ah[4], al[4], bh[4], bl[4];
#pragma unroll
        for (int t = 0; t < 4; t++) {
            int ar = wm * 64 + t * 16 + l16;
            ah[t] = *(const bf8_t*)&Ah[ar * 32 + sw];
            al[t] = *(const bf8_t*)&Al[ar * 32 + sw];
            int br = wn * 64 + t * 16 + l16;
            bh[t] = *(const bf8_t*)&Bh[br * 32 + sw];
            bl[t] = *(const bf8_t*)&Bl[br * 32 + sw];
        }
#pragma unroll
        for (int i = 0; i < 4; i++)
#pragma unroll
            for (int j = 0; j < 4; j++) {
                acc[i][j] = __builtin_amdgcn_mfma_f32_16x16x32_bf16(ah[i], bh[j], acc[i][j], 0, 0, 0);
                acc[i][j] = __builtin_amdgcn_mfma_f32_16x16x32_bf16(al[i], bh[j], acc[i][j], 0, 0, 0);
                acc[i][j] = __builtin_amdgcn_mfma_f32_16x16x32_bf16(ah[i], bl[j], acc[i][j], 0, 0, 0);
            }
    }
    // epilogue: D row(m)=quad*4+reg, col(n)=lane&15
#pragma unroll
    for (int i = 0; i < 4; i++) {
#pragma unroll
        for (int r = 0; r < 4; r++) {
            int grow = row0 + wm * 64 + i * 16 + quad * 4 + r;
            if (grow >= M) continue;
#pragma unroll
            for (int j = 0; j < 4; j++) {
                int gcol = col0 + wn * 64 + j * 16 + l16;
                if (gcol >= N) continue;
                float v = acc[i][j][r];
                if (BIAS) v += bias[gcol];
                C[(size_t)grow * N + gcol] = v;
            }
        }
    }
}

// ---------------- attention dot products per node/head ----------------
__global__ __launch_bounds__(256) void attn_dots(const float* __restrict__ h,
                                                 const float* __restrict__ att_s,
                                                 const float* __restrict__ att_d,
                                                 float* __restrict__ a_src,
                                                 float* __restrict__ a_dst, int Nn) {
    int n = blockIdx.x;
    int head = threadIdx.x >> 6;
    int lane = threadIdx.x & 63;
    const float2* hr = (const float2*)(h + (long)n * (HEADS * HID) + head * HID);
    const float2* as = (const float2*)(att_s + head * HID);
    const float2* ad = (const float2*)(att_d + head * HID);
    float ss = 0.f, sd = 0.f;
    for (int d = lane; d < HID / 2; d += 64) {
        float2 hv = hr[d], av = as[d], dv = ad[d];
        ss += hv.x * av.x + hv.y * av.y;
        sd += hv.x * dv.x + hv.y * dv.y;
    }
    for (int off = 32; off > 0; off >>= 1) {
        ss += __shfl_down(ss, off);
        sd += __shfl_down(sd, off);
    }
    if (lane == 0) {
        a_src[n * HEADS + head] = ss;
        a_dst[n * HEADS + head] = sd;
    }
}

// ---------------- per-dst-node softmax + aggregation (atomic-free, CSR) ----------------
// OUTMODE 0: write fp32 row (stride HIDP, zero K-pad) — consumed by edge_conv.
// OUTMODE 1: write split bf16 hi/lo rows — consumed directly by AMODE-1 MFMA GEMM.
template <int OUTMODE>
__global__ __launch_bounds__(256) void node_aggregate(
    const float* __restrict__ h, const float* __restrict__ asrc,
    const float* __restrict__ adst, const int* __restrict__ base,
    const int* __restrict__ esrc, const float* __restrict__ bias,
    float* __restrict__ xout, ushort* __restrict__ xhi, ushort* __restrict__ xlo,
    int Nn) {
    int wave = threadIdx.x >> 6, lane = threadIdx.x & 63;
    int n = blockIdx.x * 4 + wave;
    if (n >= Nn) return;
    int b0 = base[n], deg = base[n + 1] - b0;
    float ad[HEADS];
#pragma unroll
    for (int hh = 0; hh < HEADS; hh++) ad[hh] = adst[n * HEADS + hh];
    // pass A: per-head max
    float m[HEADS] = {-INFINITY, -INFINITY, -INFINITY, -INFINITY};
    for (int eb = 0; eb < deg; eb += 64) {
        int i = eb + lane;
        if (i < deg) {
            int s = esrc[b0 + i];
#pragma unroll
            for (int hh = 0; hh < HEADS; hh++) {
                float v = asrc[s * HEADS + hh] + ad[hh];
                v = v >= 0.f ? v : NEG_SLOPE * v;
                m[hh] = fmaxf(m[hh], v);
            }
        }
    }
#pragma unroll
    for (int off = 32; off > 0; off >>= 1)
#pragma unroll
        for (int hh = 0; hh < HEADS; hh++) m[hh] = fmaxf(m[hh], __shfl_xor(m[hh], off));
    // pass B: denom
    float sden[HEADS] = {0.f, 0.f, 0.f, 0.f};
    for (int eb = 0; eb < deg; eb += 64) {
        int i = eb + lane;
        if (i < deg) {
            int s = esrc[b0 + i];
#pragma unroll
            for (int hh = 0; hh < HEADS; hh++) {
                float v = asrc[s * HEADS + hh] + ad[hh];
                v = v >= 0.f ? v : NEG_SLOPE * v;
                sden[hh] += expf(v - m[hh]);
            }
        }
    }
#pragma unroll
    for (int off = 32; off > 0; off >>= 1)
#pragma unroll
        for (int hh = 0; hh < HEADS; hh++) sden[hh] += __shfl_xor(sden[hh], off);
    float inv[HEADS];
#pragma unroll
    for (int hh = 0; hh < HEADS; hh++) inv[hh] = 0.25f / (sden[hh] + 1e-16f);
    // pass C: weighted aggregation
    float acc0[10] = {}, acc1[10] = {}, acc2[10] = {}, acc3[10] = {};
    for (int eb = 0; eb < deg; eb += 64) {
        int i = eb + lane;
        int sreg = 0;
        float coef[HEADS] = {0.f, 0.f, 0.f, 0.f};
        if (i < deg) {
            sreg = esrc[b0 + i];
#pragma unroll
            for (int hh = 0; hh < HEADS; hh++) {
                float v = asrc[sreg * HEADS + hh] + ad[hh];
                v = v >= 0.f ? v : NEG_SLOPE * v;
                coef[hh] = expf(v - m[hh]) * inv[hh];
            }
        }
        int cnt = deg - eb < 64 ? deg - eb : 64;
        for (int j = 0; j < cnt; j++) {
            int s = __shfl(sreg, j);
            float c0 = __shfl(coef[0], j), c1 = __shfl(coef[1], j);
            float c2 = __shfl(coef[2], j), c3 = __shfl(coef[3], j);
            const float* hr = h + (size_t)s * (HEADS * HID);
#pragma unroll
            for (int t = 0; t < 10; t++) {
                int d = lane + t * 64;
                if (d < HID) {
                    acc0[t] = fmaf(c0, hr[d], acc0[t]);
                    acc1[t] = fmaf(c1, hr[HID + d], acc1[t]);
                    acc2[t] = fmaf(c2, hr[2 * HID + d], acc2[t]);
                    acc3[t] = fmaf(c3, hr[3 * HID + d], acc3[t]);
                }
            }
        }
    }
#pragma unroll
    for (int t = 0; t < 10; t++) {
        int d = lane + t * 64;
        if (d < HID) {
            float v = acc0[t] + acc1[t] + acc2[t] + acc3[t] + bias[d];
            v = v > 0.f ? v : 0.f;
            if (OUTMODE == 0) {
                xout[(size_t)n * HIDP + d] = v;
            } else {
                ushort hv = f2bf(v);
                xhi[(size_t)n * HIDP + d] = hv;
                xlo[(size_t)n * HIDP + d] = f2bf(v - bf2f(hv));
            }
        }
    }
    for (int d = HID + lane; d < HIDP; d += 64) {
        if (OUTMODE == 0) {
            xout[(size_t)n * HIDP + d] = 0.f;
        } else {
            xhi[(size_t)n * HIDP + d] = 0;
            xlo[(size_t)n * HIDP + d] = 0;
        }
    }
}

// ---------------- fused edge conv (x2 stride HIDP) -> z written as bf16 hi/lo ----------
__device__ __forceinline__ int ystag(int j) { return j + (j >> 3); }

__global__ __launch_bounds__(256) void edge_conv(const float* __restrict__ x2,
                                                 const int* __restrict__ ei,
                                                 const float* __restrict__ w4,
                                                 const float* __restrict__ b4,
                                                 const float* __restrict__ w6,
                                                 const float* __restrict__ b6,
                                                 ushort* __restrict__ zhi,
                                                 ushort* __restrict__ zlo, int E) {
    __shared__ __align__(16) float s[4][628];
    __shared__ __align__(16) float t[4][628];
    __shared__ __align__(16) float y[4][652];
    int wave = threadIdx.x >> 6;
    int lane = threadIdx.x & 63;
    int e = blockIdx.x * 4 + wave;
    bool active = (e < E);
    if (active) {
        int sidx = ei[e];
        int didx = ei[E + e];
        const float2* sp = (const float2*)(x2 + (long)sidx * HIDP);
        const float2* tp = (const float2*)(x2 + (long)didx * HIDP);
        float2* sl = (float2*)s[wave];
        float2* tl = (float2*)t[wave];
        for (int i = lane; i < HID / 2; i += 64) {
            sl[i] = sp[i];
            tl[i] = tp[i];
        }
    }
    __syncthreads();
    float bb4 = b4[0], bb6 = b6[0];
    if (active) {
        int j0 = lane * 9;
        float acc[9], sw[9], tw[9];
#pragma unroll
        for (int i = 0; i < 9; i++) {
            acc[i] = bb4;
            sw[i] = s[wave][j0 + i];
            tw[i] = t[wave][j0 + i];
        }
#pragma unroll
        for (int k = 0; k < KER; k++) {
            float ws_ = w4[k], wt_ = w4[KER + k];
#pragma unroll
            for (int i = 0; i < 9; i++) acc[i] += sw[i] * ws_ + tw[i] * wt_;
#pragma unroll
            for (int i = 0; i < 8; i++) {
                sw[i] = sw[i + 1];
                tw[i] = tw[i + 1];
            }
            sw[8] = s[wave][j0 + 9 + k];
            tw[8] = t[wave][j0 + 9 + k];
        }
#pragma unroll
        for (int i = 0; i < 9; i++)
            y[wave][ystag(j0 + i)] = acc[i] > 0.f ? acc[i] : 0.f;
    }
    __syncthreads();
    if (active) {
        int j0 = lane * 8;
        float acc[8], yw[8];
#pragma unroll
        for (int i = 0; i < 8; i++) {
            acc[i] = bb6;
            yw[i] = y[wave][ystag(j0 + i)];
        }
#pragma unroll
        for (int k = 0; k < KER; k++) {
            float wv = w6[k];
#pragma unroll
            for (int i = 0; i < 8; i++) acc[i] += yw[i] * wv;
#pragma unroll
            for (int i = 0; i < 7; i++) yw[i] = yw[i + 1];
            yw[7] = y[wave][ystag(j0 + 8 + k)];
        }
        ushort4 zh0, zh1, zl0, zl1;
        float v;
        v = acc[0] > 0.f ? acc[0] : 0.f; zh0.x = f2bf(v); zl0.x = f2bf(v - bf2f(zh0.x));
        v = acc[1] > 0.f ? acc[1] : 0.f; zh0.y = f2bf(v); zl0.y = f2bf(v - bf2f(zh0.y));
        v = acc[2] > 0.f ? acc[2] : 0.f; zh0.z = f2bf(v); zl0.z = f2bf(v - bf2f(zh0.z));
        v = acc[3] > 0.f ? acc[3] : 0.f; zh0.w = f2bf(v); zl0.w = f2bf(v - bf2f(zh0.w));
        v = acc[4] > 0.f ? acc[4] : 0.f; zh1.x = f2bf(v); zl1.x = f2bf(v - bf2f(zh1.x));
        v = acc[5] > 0.f ? acc[5] : 0.f; zh1.y = f2bf(v); zl1.y = f2bf(v - bf2f(zh1.y));
        v = acc[6] > 0.f ? acc[6] : 0.f; zh1.z = f2bf(v); zl1.z = f2bf(v - bf2f(zh1.z));
        v = acc[7] > 0.f ? acc[7] : 0.f; zh1.w = f2bf(v); zl1.w = f2bf(v - bf2f(zh1.w));
        size_t zo = (size_t)e * 512 + j0;
        *(ushort4*)&zhi[zo] = zh0;
        *(ushort4*)&zhi[zo + 4] = zh1;
        *(ushort4*)&zlo[zo] = zl0;
        *(ushort4*)&zlo[zo + 4] = zl1;
    }
}

extern "C" void kernel_launch(void* const* d_in, const int* in_sizes, int n_in,
                              void* d_out, int out_size, void* d_ws, size_t ws_size,
                              hipStream_t stream) {
    const float* x = (const float*)d_in[0];
    const int* ei = (const int*)d_in[1];  // int32
    const float* w0 = (const float*)d_in[2];
    const float* b0 = (const float*)d_in[3];
    const float* att_s0 = (const float*)d_in[4];
    const float* att_d0 = (const float*)d_in[5];
    const float* w2 = (const float*)d_in[6];
    const float* b2 = (const float*)d_in[7];
    const float* att_s1 = (const float*)d_in[8];
    const float* att_d1 = (const float*)d_in[9];
    const float* w4 = (const float*)d_in[10];
    const float* b4 = (const float*)d_in[11];
    const float* w6 = (const float*)d_in[12];
    const float* b6 = (const float*)d_in[13];
    const float* w8 = (const float*)d_in[14];
    const float* b8 = (const float*)d_in[15];
    float* out = (float*)d_out;

    const int Nn = in_sizes[0] / FIN;  // 20000
    const int E = in_sizes[1] / 2;     // 100000
    const int HD = HEADS * HID;        // 2440

    // ---- workspace layout (floats), watermark identical to proven-safe R5 ----
    float* ws = (float*)d_ws;
    size_t o = 0;
    float* buf1 = ws + o; o += (size_t)Nn * HIDP;  // layer1: x1 as bf16 hi/lo; layer2: x2 fp32
    ushort* x1hi = (ushort*)buf1;                  // Nn*HIDP bf16 (hi)  — fits buf1 exactly
    ushort* x1lo = x1hi + (size_t)Nn * HIDP;       // Nn*HIDP bf16 (lo)
    ushort* w8hi = (ushort*)(ws + o);
    ushort* w8lo = w8hi + (size_t)NOUT * 512; o += (size_t)NOUT * 512;
    // z (bf16 hi/lo) overlays everything from here on (sort/attn/h all dead by conv time)
    ushort* zhi = (ushort*)(ws + o);
    ushort* zlo = zhi + (size_t)E * 512;
    int* base = (int*)(ws + o); o += (size_t)Nn + 4;
    int* cursor = (int*)(ws + o); o += (size_t)Nn;  // also hist
    int* esrc = (int*)(ws + o); o += (size_t)E;
    float* asrc = ws + o; o += (size_t)Nn * HEADS;
    float* adst = ws + o; o += (size_t)Nn * HEADS;
    ushort* w0hi = (ushort*)(ws + o);
    ushort* w0lo = w0hi + (size_t)HD * FIN; o += (size_t)HD * FIN;
    ushort* w2hi = (ushort*)(ws + o);
    ushort* w2lo = w2hi + (size_t)HD * HIDP; o += (size_t)HD * HIDP;
    float* h = ws + o;  // Nn*2440 fp32

    int edgeGrid = (E + 255) / 256;
    int nodeWaveGrid = (Nn + 3) / 4;
    int edgeConvGrid = (E + 3) / 4;
    dim3 gGemmL((HD + 127) / 128, (Nn + 127) / 128);   // 20 x 157
    dim3 gGemmF((NOUT + 127) / 128, (E + 127) / 128);  // 1 x 782

    // ---- one-time: weight split + edge sort by dst ----
    split_pad<<<((HD * FIN) + 255) / 256, 256, 0, stream>>>(w0, w0hi, w0lo, HD, FIN, FIN);
    split_pad<<<((HD * HIDP) + 255) / 256, 256, 0, stream>>>(w2, w2hi, w2lo, HD, HID, HIDP);
    split_pad<<<((NOUT * 512) + 255) / 256, 256, 0, stream>>>(w8, w8hi, w8lo, NOUT, 512, 512);
    fill_val<<<(Nn + 255) / 256, 256, 0, stream>>>((float*)cursor, 0.f, Nn);  // hist=0
    hist_k<<<edgeGrid, 256, 0, stream>>>(ei, cursor, E);
    scan_k<<<1, 1024, 0, stream>>>(cursor, base, Nn);
    copy_int<<<(Nn + 255) / 256, 256, 0, stream>>>(base, cursor, Nn);
    scatter_k<<<edgeGrid, 256, 0, stream>>>(ei, cursor, esrc, E);

    // ---------- GAT layer 1 ----------
    gemm_mfma<0, false><<<gGemmL, 256, 0, stream>>>(x, nullptr, nullptr, w0hi, w0lo, nullptr,
                                                    h, Nn, HD, FIN);
    attn_dots<<<Nn, 256, 0, stream>>>(h, att_s0, att_d0, asrc, adst, Nn);
    node_aggregate<1><<<nodeWaveGrid, 256, 0, stream>>>(h, asrc, adst, base, esrc, b0,
                                                        nullptr, x1hi, x1lo, Nn);

    // ---------- GAT layer 2 (A pre-split: no conversion VALU in hot loop) ----------
    gemm_mfma<1, false><<<gGemmL, 256, 0, stream>>>(nullptr, x1hi, x1lo, w2hi, w2lo, nullptr,
                                                    h, Nn, HD, HIDP);
    attn_dots<<<Nn, 256, 0, stream>>>(h, att_s1, att_d1, asrc, adst, Nn);
    node_aggregate<0><<<nodeWaveGrid, 256, 0, stream>>>(h, asrc, adst, base, esrc, b2,
                                                        buf1, nullptr, nullptr, Nn);

    // ---------- edge conv -> z as bf16 hi/lo ----------
    edge_conv<<<edgeConvGrid, 256, 0, stream>>>(buf1, ei, w4, b4, w6, b6, zhi, zlo, E);

    // ---------- final linear: out = z @ w8^T + b8 ----------
    gemm_mfma<1, true><<<gGemmF, 256, 0, stream>>>(nullptr, zhi, zlo, w8hi, w8lo, b8,
                                                   out, E, NOUT, 512);
}

// Round 7
// 1124.446 us; speedup vs baseline: 4.2787x; 1.0399x over previous
//
#include <hip/hip_runtime.h>
#include <math.h>

#define HEADS 4
#define HID 610
#define HIDP 640   // K-padded row stride for MFMA (mult of 32)
#define FIN 128
#define KER 50
#define NOUT 86
#define NEG_SLOPE 0.2f

typedef short bf8_t __attribute__((ext_vector_type(8)));  // 8 bf16 (4 VGPRs)
typedef float f4_t __attribute__((ext_vector_type(4)));   // MFMA C/D

__device__ __forceinline__ ushort f2bf(float f) {  // RNE fp32->bf16
    unsigned u = __float_as_uint(f);
    unsigned r = (u + 0x7FFFu + ((u >> 16) & 1u)) >> 16;
    return (ushort)r;
}
__device__ __forceinline__ float bf2f(ushort b) { return __uint_as_float(((unsigned)b) << 16); }

// ---------------- utility ----------------
__global__ void fill_val(float* __restrict__ p, float v, long n) {
    long i = (long)blockIdx.x * blockDim.x + threadIdx.x;
    if (i < n) p[i] = v;
}

__global__ void copy_int(const int* __restrict__ a, int* __restrict__ b, int n) {
    int i = blockIdx.x * blockDim.x + threadIdx.x;
    if (i < n) b[i] = a[i];
}

// ---------------- edge sort by dst: histogram / scan / scatter ----------------
__global__ void hist_k(const int* __restrict__ ei, int* __restrict__ hist, int E) {
    int e = blockIdx.x * blockDim.x + threadIdx.x;
    if (e < E) atomicAdd(&hist[ei[E + e]], 1);
}

__global__ __launch_bounds__(1024) void scan_k(const int* __restrict__ hist,
                                               int* __restrict__ base, int Nn) {
    __shared__ int tmp[1024];
    __shared__ int carry;
    if (threadIdx.x == 0) carry = 0;
    __syncthreads();
    for (int c0 = 0; c0 < Nn; c0 += 1024) {
        int i = c0 + threadIdx.x;
        int v = (i < Nn) ? hist[i] : 0;
        tmp[threadIdx.x] = v;
        __syncthreads();
        for (int off = 1; off < 1024; off <<= 1) {
            int t = (threadIdx.x >= off) ? tmp[threadIdx.x - off] : 0;
            __syncthreads();
            tmp[threadIdx.x] += t;
            __syncthreads();
        }
        if (i < Nn) base[i] = carry + tmp[threadIdx.x] - v;  // exclusive
        __syncthreads();
        if (threadIdx.x == 1023) carry += tmp[1023];
        __syncthreads();
    }
    if (threadIdx.x == 0) base[Nn] = carry;
}

__global__ void scatter_k(const int* __restrict__ ei, int* __restrict__ cursor,
                          int* __restrict__ esrc, int E) {
    int e = blockIdx.x * blockDim.x + threadIdx.x;
    if (e >= E) return;
    int d = ei[E + e];
    int pos = atomicAdd(&cursor[d], 1);
    esrc[pos] = ei[e];
}

// ---------------- split fp32 -> bf16 hi/lo with K padding ----------------
__global__ void split_pad(const float* __restrict__ in, ushort* __restrict__ hi,
                          ushort* __restrict__ lo, int R, int K, int Kp) {
    long i = (long)blockIdx.x * blockDim.x + threadIdx.x;
    if (i >= (long)R * Kp) return;
    int r = (int)(i / Kp), c = (int)(i % Kp);
    float v = (c < K) ? in[(long)r * K + c] : 0.f;
    ushort h = f2bf(v);
    hi[i] = h;
    lo[i] = f2bf(v - bf2f(h));
}

// ---------------- split-bf16 MFMA GEMM: C[M,N] = A[M,Kp] * B[N,Kp]^T (+bias) ----------------
// LDS layout: rows of 32 ushorts (64B = 4 chunks of 16B); chunk c of row r stored at
// chunk position c ^ ((r>>1)&3). Staging writes stay contiguous within each row;
// fragment ds_read_b128 lands exactly 2 lanes/bank (free). Register prefetch
// double-buffers the global staging loads across the MFMA loop.
template <int AMODE, bool BIAS>
__global__ __launch_bounds__(256) void gemm_mfma(const float* __restrict__ A,
                                                 const ushort* __restrict__ Aghi,
                                                 const ushort* __restrict__ Aglo,
                                                 const ushort* __restrict__ Bghi,
                                                 const ushort* __restrict__ Bglo,
                                                 const float* __restrict__ bias,
                                                 float* __restrict__ C,
                                                 int M, int N, int Kp) {
    __shared__ __align__(16) ushort Ah[128 * 32];
    __shared__ __align__(16) ushort Al[128 * 32];
    __shared__ __align__(16) ushort Bh[128 * 32];
    __shared__ __align__(16) ushort Bl[128 * 32];
    int tid = threadIdx.x;
    int wave = tid >> 6, lane = tid & 63;
    int quad = lane >> 4, l16 = lane & 15;
    int wm = wave & 1, wn = wave >> 1;
    int row0 = blockIdx.y * 128, col0 = blockIdx.x * 128;

    float4 pa0[4];
    uint4 pah[2], pal[2], pbh[2], pbl[2];

    auto loadA = [&](int k0) {
        if (AMODE == 0) {
#pragma unroll
            for (int q = 0; q < 4; q++) {
                int p = tid + q * 256;
                int r = p >> 3, c4 = (p & 7) << 2;
                int gr = row0 + r;
                pa0[q] = (gr < M) ? *(const float4*)(A + (size_t)gr * Kp + k0 + c4)
                                  : make_float4(0.f, 0.f, 0.f, 0.f);
            }
        } else {
#pragma unroll
            for (int q = 0; q < 2; q++) {
                int p = tid + q * 256;
                int r = p >> 2, c = p & 3;
                int gr = row0 + r;
                if (gr < M) {
                    pah[q] = *(const uint4*)(Aghi + (size_t)gr * Kp + k0 + c * 8);
                    pal[q] = *(const uint4*)(Aglo + (size_t)gr * Kp + k0 + c * 8);
                } else {
                    pah[q] = make_uint4(0, 0, 0, 0);
                    pal[q] = make_uint4(0, 0, 0, 0);
                }
            }
        }
    };
    auto loadB = [&](int k0) {
#pragma unroll
        for (int q = 0; q < 2; q++) {
            int p = tid + q * 256;
            int r = p >> 2, c = p & 3;
            int gr = col0 + r;
            if (gr < N) {
                pbh[q] = *(const uint4*)(Bghi + (size_t)gr * Kp + k0 + c * 8);
                pbl[q] = *(const uint4*)(Bglo + (size_t)gr * Kp + k0 + c * 8);
            } else {
                pbh[q] = make_uint4(0, 0, 0, 0);
                pbl[q] = make_uint4(0, 0, 0, 0);
            }
        }
    };
    auto writeLDS = [&]() {
        if (AMODE == 0) {
#pragma unroll
            for (int q = 0; q < 4; q++) {
                int p = tid + q * 256;
                int r = p >> 3, m = p & 7;
                int pos = r * 32 + ((((m >> 1)) ^ ((r >> 1) & 3)) << 3) + ((m & 1) << 2);
                float4 v = pa0[q];
                ushort4 hv, lv;
                hv.x = f2bf(v.x); lv.x = f2bf(v.x - bf2f(hv.x));
                hv.y = f2bf(v.y); lv.y = f2bf(v.y - bf2f(hv.y));
                hv.z = f2bf(v.z); lv.z = f2bf(v.z - bf2f(hv.z));
                hv.w = f2bf(v.w); lv.w = f2bf(v.w - bf2f(hv.w));
                *(ushort4*)&Ah[pos] = hv;
                *(ushort4*)&Al[pos] = lv;
            }
        } else {
#pragma unroll
            for (int q = 0; q < 2; q++) {
                int p = tid + q * 256;
                int r = p >> 2, c = p & 3;
                int pos = r * 32 + ((c ^ ((r >> 1) & 3)) << 3);
                *(uint4*)&Ah[pos] = pah[q];
                *(uint4*)&Al[pos] = pal[q];
            }
        }
#pragma unroll
        for (int q = 0; q < 2; q++) {
            int p = tid + q * 256;
            int r = p >> 2, c = p & 3;
            int pos = r * 32 + ((c ^ ((r >> 1) & 3)) << 3);
            *(uint4*)&Bh[pos] = pbh[q];
            *(uint4*)&Bl[pos] = pbl[q];
        }
    };

    f4_t acc[4][4];
#pragma unroll
    for (int i = 0; i < 4; i++)
#pragma unroll
        for (int j = 0; j < 4; j++) acc[i][j] = (f4_t){0.f, 0.f, 0.f, 0.f};

    loadA(0);
    loadB(0);
    int sw = (quad ^ ((l16 >> 1) & 3)) << 3;
    for (int k0 = 0; k0 < Kp; k0 += 32) {
        __syncthreads();
        writeLDS();
        __syncthreads();
        if (k0 + 32 < Kp) {
            loadA(k0 + 32);
            loadB(k0 + 32);
        }
        bf8_t ah[4], al[4], bh[4], bl[4];
#pragma unroll
        for (int t = 0; t < 4; t++) {
            int ar = wm * 64 + t * 16 + l16;
            ah[t] = *(const bf8_t*)&Ah[ar * 32 + sw];
            al[t] = *(const bf8_t*)&Al[ar * 32 + sw];
            int br = wn * 64 + t * 16 + l16;
            bh[t] = *(const bf8_t*)&Bh[br * 32 + sw];
            bl[t] = *(const bf8_t*)&Bl[br * 32 + sw];
        }
#pragma unroll
        for (int i = 0; i < 4; i++)
#pragma unroll
            for (int j = 0; j < 4; j++) {
                acc[i][j] = __builtin_amdgcn_mfma_f32_16x16x32_bf16(ah[i], bh[j], acc[i][j], 0, 0, 0);
                acc[i][j] = __builtin_amdgcn_mfma_f32_16x16x32_bf16(al[i], bh[j], acc[i][j], 0, 0, 0);
                acc[i][j] = __builtin_amdgcn_mfma_f32_16x16x32_bf16(ah[i], bl[j], acc[i][j], 0, 0, 0);
            }
    }
    // epilogue: D row(m)=quad*4+reg, col(n)=lane&15
#pragma unroll
    for (int i = 0; i < 4; i++) {
#pragma unroll
        for (int r = 0; r < 4; r++) {
            int grow = row0 + wm * 64 + i * 16 + quad * 4 + r;
            if (grow >= M) continue;
#pragma unroll
            for (int j = 0; j < 4; j++) {
                int gcol = col0 + wn * 64 + j * 16 + l16;
                if (gcol >= N) continue;
                float v = acc[i][j][r];
                if (BIAS) v += bias[gcol];
                C[(size_t)grow * N + gcol] = v;
            }
        }
    }
}

// ---------------- attention dot products per node/head ----------------
__global__ __launch_bounds__(256) void attn_dots(const float* __restrict__ h,
                                                 const float* __restrict__ att_s,
                                                 const float* __restrict__ att_d,
                                                 float* __restrict__ a_src,
                                                 float* __restrict__ a_dst, int Nn) {
    int n = blockIdx.x;
    int head = threadIdx.x >> 6;
    int lane = threadIdx.x & 63;
    const float2* hr = (const float2*)(h + (long)n * (HEADS * HID) + head * HID);
    const float2* as = (const float2*)(att_s + head * HID);
    const float2* ad = (const float2*)(att_d + head * HID);
    float ss = 0.f, sd = 0.f;
    for (int d = lane; d < HID / 2; d += 64) {
        float2 hv = hr[d], av = as[d], dv = ad[d];
        ss += hv.x * av.x + hv.y * av.y;
        sd += hv.x * dv.x + hv.y * dv.y;
    }
    for (int off = 32; off > 0; off >>= 1) {
        ss += __shfl_down(ss, off);
        sd += __shfl_down(sd, off);
    }
    if (lane == 0) {
        a_src[n * HEADS + head] = ss;
        a_dst[n * HEADS + head] = sd;
    }
}

// ---------------- per-dst-node softmax + aggregation (atomic-free, CSR) ----------------
template <int OUTMODE>
__global__ __launch_bounds__(256) void node_aggregate(
    const float* __restrict__ h, const float* __restrict__ asrc,
    const float* __restrict__ adst, const int* __restrict__ base,
    const int* __restrict__ esrc, const float* __restrict__ bias,
    float* __restrict__ xout, ushort* __restrict__ xhi, ushort* __restrict__ xlo,
    int Nn) {
    int wave = threadIdx.x >> 6, lane = threadIdx.x & 63;
    int n = blockIdx.x * 4 + wave;
    if (n >= Nn) return;
    int b0 = base[n], deg = base[n + 1] - b0;
    float ad[HEADS];
#pragma unroll
    for (int hh = 0; hh < HEADS; hh++) ad[hh] = adst[n * HEADS + hh];
    float m[HEADS] = {-INFINITY, -INFINITY, -INFINITY, -INFINITY};
    for (int eb = 0; eb < deg; eb += 64) {
        int i = eb + lane;
        if (i < deg) {
            int s = esrc[b0 + i];
#pragma unroll
            for (int hh = 0; hh < HEADS; hh++) {
                float v = asrc[s * HEADS + hh] + ad[hh];
                v = v >= 0.f ? v : NEG_SLOPE * v;
                m[hh] = fmaxf(m[hh], v);
            }
        }
    }
#pragma unroll
    for (int off = 32; off > 0; off >>= 1)
#pragma unroll
        for (int hh = 0; hh < HEADS; hh++) m[hh] = fmaxf(m[hh], __shfl_xor(m[hh], off));
    float sden[HEADS] = {0.f, 0.f, 0.f, 0.f};
    for (int eb = 0; eb < deg; eb += 64) {
        int i = eb + lane;
        if (i < deg) {
            int s = esrc[b0 + i];
#pragma unroll
            for (int hh = 0; hh < HEADS; hh++) {
                float v = asrc[s * HEADS + hh] + ad[hh];
                v = v >= 0.f ? v : NEG_SLOPE * v;
                sden[hh] += expf(v - m[hh]);
            }
        }
    }
#pragma unroll
    for (int off = 32; off > 0; off >>= 1)
#pragma unroll
        for (int hh = 0; hh < HEADS; hh++) sden[hh] += __shfl_xor(sden[hh], off);
    float inv[HEADS];
#pragma unroll
    for (int hh = 0; hh < HEADS; hh++) inv[hh] = 0.25f / (sden[hh] + 1e-16f);
    float acc0[10] = {}, acc1[10] = {}, acc2[10] = {}, acc3[10] = {};
    for (int eb = 0; eb < deg; eb += 64) {
        int i = eb + lane;
        int sreg = 0;
        float coef[HEADS] = {0.f, 0.f, 0.f, 0.f};
        if (i < deg) {
            sreg = esrc[b0 + i];
#pragma unroll
            for (int hh = 0; hh < HEADS; hh++) {
                float v = asrc[sreg * HEADS + hh] + ad[hh];
                v = v >= 0.f ? v : NEG_SLOPE * v;
                coef[hh] = expf(v - m[hh]) * inv[hh];
            }
        }
        int cnt = deg - eb < 64 ? deg - eb : 64;
        for (int j = 0; j < cnt; j++) {
            int s = __shfl(sreg, j);
            float c0 = __shfl(coef[0], j), c1 = __shfl(coef[1], j);
            float c2 = __shfl(coef[2], j), c3 = __shfl(coef[3], j);
            const float* hr = h + (size_t)s * (HEADS * HID);
#pragma unroll
            for (int t = 0; t < 10; t++) {
                int d = lane + t * 64;
                if (d < HID) {
                    acc0[t] = fmaf(c0, hr[d], acc0[t]);
                    acc1[t] = fmaf(c1, hr[HID + d], acc1[t]);
                    acc2[t] = fmaf(c2, hr[2 * HID + d], acc2[t]);
                    acc3[t] = fmaf(c3, hr[3 * HID + d], acc3[t]);
                }
            }
        }
    }
#pragma unroll
    for (int t = 0; t < 10; t++) {
        int d = lane + t * 64;
        if (d < HID) {
            float v = acc0[t] + acc1[t] + acc2[t] + acc3[t] + bias[d];
            v = v > 0.f ? v : 0.f;
            if (OUTMODE == 0) {
                xout[(size_t)n * HIDP + d] = v;
            } else {
                ushort hv = f2bf(v);
                xhi[(size_t)n * HIDP + d] = hv;
                xlo[(size_t)n * HIDP + d] = f2bf(v - bf2f(hv));
            }
        }
    }
    for (int d = HID + lane; d < HIDP; d += 64) {
        if (OUTMODE == 0) {
            xout[(size_t)n * HIDP + d] = 0.f;
        } else {
            xhi[(size_t)n * HIDP + d] = 0;
            xlo[(size_t)n * HIDP + d] = 0;
        }
    }
}

// ---------------- fused edge conv: circular register windows, zero shift-movs ----------
// st[j] = {s[j], t[j]} interleaved in LDS (one ds_read_b64 feeds both channels).
// y staggered: idx(j) = j + (j>>3) (breaks conv2 stride-8 conflict).
__device__ __forceinline__ int ystag(int j) { return j + (j >> 3); }

__global__ __launch_bounds__(256) void edge_conv(const float* __restrict__ x2,
                                                 const int* __restrict__ ei,
                                                 const float* __restrict__ w4,
                                                 const float* __restrict__ b4,
                                                 const float* __restrict__ w6,
                                                 const float* __restrict__ b6,
                                                 ushort* __restrict__ zhi,
                                                 ushort* __restrict__ zlo, int E) {
    __shared__ __align__(16) float2 st[4][632];
    __shared__ __align__(16) float y[4][652];
    int wave = threadIdx.x >> 6;
    int lane = threadIdx.x & 63;
    int e = blockIdx.x * 4 + wave;
    bool active = (e < E);
    if (active) {
        int sidx = ei[e];
        int didx = ei[E + e];
        const float2* sp = (const float2*)(x2 + (long)sidx * HIDP);
        const float2* tp = (const float2*)(x2 + (long)didx * HIDP);
        for (int i = lane; i < HID / 2; i += 64) {  // 305 pairs
            float2 sv = sp[i], tv = tp[i];
            *(float4*)&st[wave][2 * i] = make_float4(sv.x, tv.x, sv.y, tv.y);
        }
    }
    __syncthreads();
    float bb4 = b4[0], bb6 = b6[0];
    if (active) {
        // conv1: 9 outputs/lane, circular window W[18], groups of 9 taps (mod-18 indices
        // are compile-time after full unroll -> no register-shift movs)
        int j0 = lane * 9;  // 0..567
        float acc[9];
        float2 W[18];
#pragma unroll
        for (int i = 0; i < 9; i++) acc[i] = bb4;
#pragma unroll
        for (int p = 0; p < 18; p++) W[p] = st[wave][j0 + p];
#pragma unroll
        for (int g = 0; g < 6; g++) {
#pragma unroll
            for (int mm = 0; mm < 9; mm++) {
                int k = 9 * g + mm;
                if (k < KER) {
                    float ws_ = w4[k], wt_ = w4[KER + k];
#pragma unroll
                    for (int i = 0; i < 9; i++) {
                        float2 v = W[(9 * g + mm + i) % 18];
                        acc[i] = fmaf(v.x, ws_, acc[i]);
                        acc[i] = fmaf(v.y, wt_, acc[i]);
                    }
                }
            }
            if (g < 5) {
#pragma unroll
                for (int p = 0; p < 9; p++)
                    W[(9 * g + p) % 18] = st[wave][j0 + 9 * g + 18 + p];  // max j0+62 <= 629
            }
        }
#pragma unroll
        for (int i = 0; i < 9; i++)
            y[wave][ystag(j0 + i)] = acc[i] > 0.f ? acc[i] : 0.f;
    }
    __syncthreads();
    if (active) {
        // conv2: 8 outputs/lane, circular window Y[16], groups of 8 taps
        int j0 = lane * 8;  // 0..504
        float acc[8];
        float Y[16];
#pragma unroll
        for (int i = 0; i < 8; i++) acc[i] = bb6;
#pragma unroll
        for (int p = 0; p < 16; p++) Y[p] = y[wave][ystag(j0 + p)];
#pragma unroll
        for (int g = 0; g < 7; g++) {
#pragma unroll
            for (int mm = 0; mm < 8; mm++) {
                int k = 8 * g + mm;
                if (k < KER) {
                    float wv = w6[k];
#pragma unroll
                    for (int i = 0; i < 8; i++)
                        acc[i] = fmaf(Y[(8 * g + mm + i) % 16], wv, acc[i]);
                }
            }
            if (g < 6) {
#pragma unroll
                for (int p = 0; p < 8; p++)
                    Y[(8 * g + p) % 16] = y[wave][ystag(j0 + 8 * g + 16 + p)];  // max ystag(567)=637
            }
        }
        ushort4 zh0, zh1, zl0, zl1;
        float v;
        v = acc[0] > 0.f ? acc[0] : 0.f; zh0.x = f2bf(v); zl0.x = f2bf(v - bf2f(zh0.x));
        v = acc[1] > 0.f ? acc[1] : 0.f; zh0.y = f2bf(v); zl0.y = f2bf(v - bf2f(zh0.y));
        v = acc[2] > 0.f ? acc[2] : 0.f; zh0.z = f2bf(v); zl0.z = f2bf(v - bf2f(zh0.z));
        v = acc[3] > 0.f ? acc[3] : 0.f; zh0.w = f2bf(v); zl0.w = f2bf(v - bf2f(zh0.w));
        v = acc[4] > 0.f ? acc[4] : 0.f; zh1.x = f2bf(v); zl1.x = f2bf(v - bf2f(zh1.x));
        v = acc[5] > 0.f ? acc[5] : 0.f; zh1.y = f2bf(v); zl1.y = f2bf(v - bf2f(zh1.y));
        v = acc[6] > 0.f ? acc[6] : 0.f; zh1.z = f2bf(v); zl1.z = f2bf(v - bf2f(zh1.z));
        v = acc[7] > 0.f ? acc[7] : 0.f; zh1.w = f2bf(v); zl1.w = f2bf(v - bf2f(zh1.w));
        size_t zo = (size_t)e * 512 + j0;
        *(ushort4*)&zhi[zo] = zh0;
        *(ushort4*)&zhi[zo + 4] = zh1;
        *(ushort4*)&zlo[zo] = zl0;
        *(ushort4*)&zlo[zo + 4] = zl1;
    }
}

extern "C" void kernel_launch(void* const* d_in, const int* in_sizes, int n_in,
                              void* d_out, int out_size, void* d_ws, size_t ws_size,
                              hipStream_t stream) {
    const float* x = (const float*)d_in[0];
    const int* ei = (const int*)d_in[1];  // int32
    const float* w0 = (const float*)d_in[2];
    const float* b0 = (const float*)d_in[3];
    const float* att_s0 = (const float*)d_in[4];
    const float* att_d0 = (const float*)d_in[5];
    const float* w2 = (const float*)d_in[6];
    const float* b2 = (const float*)d_in[7];
    const float* att_s1 = (const float*)d_in[8];
    const float* att_d1 = (const float*)d_in[9];
    const float* w4 = (const float*)d_in[10];
    const float* b4 = (const float*)d_in[11];
    const float* w6 = (const float*)d_in[12];
    const float* b6 = (const float*)d_in[13];
    const float* w8 = (const float*)d_in[14];
    const float* b8 = (const float*)d_in[15];
    float* out = (float*)d_out;

    const int Nn = in_sizes[0] / FIN;  // 20000
    const int E = in_sizes[1] / 2;     // 100000
    const int HD = HEADS * HID;        // 2440

    // ---- workspace layout (floats), watermark identical to proven-safe R5/R6 ----
    float* ws = (float*)d_ws;
    size_t o = 0;
    float* buf1 = ws + o; o += (size_t)Nn * HIDP;  // layer1: x1 as bf16 hi/lo; layer2: x2 fp32
    ushort* x1hi = (ushort*)buf1;                  // Nn*HIDP bf16 (hi)  — fits buf1 exactly
    ushort* x1lo = x1hi + (size_t)Nn * HIDP;       // Nn*HIDP bf16 (lo)
    ushort* w8hi = (ushort*)(ws + o);
    ushort* w8lo = w8hi + (size_t)NOUT * 512; o += (size_t)NOUT * 512;
    // z (bf16 hi/lo) overlays everything from here on (sort/attn/h all dead by conv time)
    ushort* zhi = (ushort*)(ws + o);
    ushort* zlo = zhi + (size_t)E * 512;
    int* base = (int*)(ws + o); o += (size_t)Nn + 4;
    int* cursor = (int*)(ws + o); o += (size_t)Nn;  // also hist
    int* esrc = (int*)(ws + o); o += (size_t)E;
    float* asrc = ws + o; o += (size_t)Nn * HEADS;
    float* adst = ws + o; o += (size_t)Nn * HEADS;
    ushort* w0hi = (ushort*)(ws + o);
    ushort* w0lo = w0hi + (size_t)HD * FIN; o += (size_t)HD * FIN;
    ushort* w2hi = (ushort*)(ws + o);
    ushort* w2lo = w2hi + (size_t)HD * HIDP; o += (size_t)HD * HIDP;
    float* h = ws + o;  // Nn*2440 fp32

    int edgeGrid = (E + 255) / 256;
    int nodeWaveGrid = (Nn + 3) / 4;
    int edgeConvGrid = (E + 3) / 4;
    dim3 gGemmL((HD + 127) / 128, (Nn + 127) / 128);   // 20 x 157
    dim3 gGemmF((NOUT + 127) / 128, (E + 127) / 128);  // 1 x 782

    // ---- one-time: weight split + edge sort by dst ----
    split_pad<<<((HD * FIN) + 255) / 256, 256, 0, stream>>>(w0, w0hi, w0lo, HD, FIN, FIN);
    split_pad<<<((HD * HIDP) + 255) / 256, 256, 0, stream>>>(w2, w2hi, w2lo, HD, HID, HIDP);
    split_pad<<<((NOUT * 512) + 255) / 256, 256, 0, stream>>>(w8, w8hi, w8lo, NOUT, 512, 512);
    fill_val<<<(Nn + 255) / 256, 256, 0, stream>>>((float*)cursor, 0.f, Nn);  // hist=0
    hist_k<<<edgeGrid, 256, 0, stream>>>(ei, cursor, E);
    scan_k<<<1, 1024, 0, stream>>>(cursor, base, Nn);
    copy_int<<<(Nn + 255) / 256, 256, 0, stream>>>(base, cursor, Nn);
    scatter_k<<<edgeGrid, 256, 0, stream>>>(ei, cursor, esrc, E);

    // ---------- GAT layer 1 ----------
    gemm_mfma<0, false><<<gGemmL, 256, 0, stream>>>(x, nullptr, nullptr, w0hi, w0lo, nullptr,
                                                    h, Nn, HD, FIN);
    attn_dots<<<Nn, 256, 0, stream>>>(h, att_s0, att_d0, asrc, adst, Nn);
    node_aggregate<1><<<nodeWaveGrid, 256, 0, stream>>>(h, asrc, adst, base, esrc, b0,
                                                        nullptr, x1hi, x1lo, Nn);

    // ---------- GAT layer 2 (A pre-split: no conversion VALU in hot loop) ----------
    gemm_mfma<1, false><<<gGemmL, 256, 0, stream>>>(nullptr, x1hi, x1lo, w2hi, w2lo, nullptr,
                                                    h, Nn, HD, HIDP);
    attn_dots<<<Nn, 256, 0, stream>>>(h, att_s1, att_d1, asrc, adst, Nn);
    node_aggregate<0><<<nodeWaveGrid, 256, 0, stream>>>(h, asrc, adst, base, esrc, b2,
                                                        buf1, nullptr, nullptr, Nn);

    // ---------- edge conv -> z as bf16 hi/lo ----------
    edge_conv<<<edgeConvGrid, 256, 0, stream>>>(buf1, ei, w4, b4, w6, b6, zhi, zlo, E);

    // ---------- final linear: out = z @ w8^T + b8 ----------
    gemm_mfma<1, true><<<gGemmF, 256, 0, stream>>>(nullptr, zhi, zlo, w8hi, w8lo, b8,
                                                   out, E, NOUT, 512);
}